// Round 1
// baseline (956.949 us; speedup 1.0000x reference)
//
#include <hip/hip_runtime.h>

#define ACT_NONE 0
#define ACT_ELU  1
#define ACT_RELU 2
#define ACT_TANH 3

__device__ __forceinline__ float apply_act(float v, int act) {
    if (act == ACT_ELU)  return v > 0.f ? v : expm1f(v);
    if (act == ACT_RELU) return fmaxf(v, 0.f);
    if (act == ACT_TANH) return tanhf(v);
    return v;
}

// C[M,N] = act(A[M,K] @ B[K,N] + bias). 64x64 tile, 256 thr, 4x4 micro-tile.
// Requires K % 16 == 0. M,N handled with guards.
__global__ __launch_bounds__(256) void gemm_kernel(
    const float* __restrict__ A, const float* __restrict__ B,
    const float* __restrict__ bias, float* __restrict__ C,
    int M, int K, int N, int act) {
    // stride 72 floats = 288B: 16B-aligned for float4 reads, bank-spread writes
    __shared__ __align__(16) float As[16][72]; // As[k][m]
    __shared__ __align__(16) float Bs[16][72]; // Bs[k][n]
    const int tid = threadIdx.x;
    const int tx = tid & 15, ty = tid >> 4;
    const int bm = blockIdx.y * 64, bn = blockIdx.x * 64;
    float acc[4][4] = {};
    for (int k0 = 0; k0 < K; k0 += 16) {
        // A tile: 64 m x 16 k. thread -> m = tid>>2, kq = tid&3 (float4 over k)
        {
            int m = tid >> 2, kq = tid & 3;
            int gm = bm + m;
            float4 v = make_float4(0.f, 0.f, 0.f, 0.f);
            if (gm < M)
                v = *reinterpret_cast<const float4*>(&A[(size_t)gm * K + k0 + kq * 4]);
            As[kq * 4 + 0][m] = v.x;
            As[kq * 4 + 1][m] = v.y;
            As[kq * 4 + 2][m] = v.z;
            As[kq * 4 + 3][m] = v.w;
        }
        // B tile: 16 k x 64 n. thread -> kk = tid>>4, nq = tid&15 (float4 over n)
        {
            int kk = tid >> 4, nq = tid & 15;
            int gn = bn + nq * 4;
            float4 v;
            if (gn + 3 < N) {
                v = *reinterpret_cast<const float4*>(&B[(size_t)(k0 + kk) * N + gn]);
            } else {
                v.x = (gn + 0 < N) ? B[(size_t)(k0 + kk) * N + gn + 0] : 0.f;
                v.y = (gn + 1 < N) ? B[(size_t)(k0 + kk) * N + gn + 1] : 0.f;
                v.z = (gn + 2 < N) ? B[(size_t)(k0 + kk) * N + gn + 2] : 0.f;
                v.w = (gn + 3 < N) ? B[(size_t)(k0 + kk) * N + gn + 3] : 0.f;
            }
            *reinterpret_cast<float4*>(&Bs[kk][nq * 4]) = v;
        }
        __syncthreads();
        #pragma unroll
        for (int kk = 0; kk < 16; ++kk) {
            float4 a4 = *reinterpret_cast<const float4*>(&As[kk][ty * 4]);
            float4 b4 = *reinterpret_cast<const float4*>(&Bs[kk][tx * 4]);
            float a[4] = {a4.x, a4.y, a4.z, a4.w};
            float b[4] = {b4.x, b4.y, b4.z, b4.w};
            #pragma unroll
            for (int i = 0; i < 4; ++i)
                #pragma unroll
                for (int j = 0; j < 4; ++j) acc[i][j] += a[i] * b[j];
        }
        __syncthreads();
    }
    #pragma unroll
    for (int i = 0; i < 4; ++i) {
        int row = bm + ty * 4 + i;
        if (row >= M) continue;
        #pragma unroll
        for (int j = 0; j < 4; ++j) {
            int col = bn + tx * 4 + j;
            if (col >= N) continue;
            float v = acc[i][j] + (bias ? bias[col] : 0.f);
            C[(size_t)row * N + col] = apply_act(v, act);
        }
    }
}

// h_agg[row] = (sum_{j: nei[row][j]!=0} h_nei[j]) / max(count,1)   (nei entries are 0/1)
__global__ __launch_bounds__(256) void neiagg_kernel(
    const float* __restrict__ nei, const float* __restrict__ hn,
    float* __restrict__ hagg) {
    const int row = blockIdx.x, t = threadIdx.x;
    __shared__ int idxs[256];
    __shared__ int cnt;
    if (t == 0) cnt = 0;
    __syncthreads();
    const float* nr = nei + (size_t)row * 4096;
    for (int j = t; j < 4096; j += 256) {
        if (nr[j] != 0.f) {
            int s = atomicAdd(&cnt, 1);
            if (s < 256) idxs[s] = j;
        }
    }
    __syncthreads();
    int n = cnt < 256 ? cnt : 256;
    float inv = 1.f / fmaxf((float)cnt, 1.f);
    for (int c = t; c < 512; c += 256) {
        float acc = 0.f;
        for (int k = 0; k < n; ++k) acc += hn[(size_t)idxs[k] * 512 + c];
        hagg[(size_t)row * 512 + c] = acc * inv;
    }
}

// views = elu(h_tar + t); masks = elu(h_mask + t)
__global__ void addelu_kernel(const float* __restrict__ ht, const float* __restrict__ hm,
                              const float* __restrict__ tt, float* __restrict__ vout,
                              float* __restrict__ mout, int n) {
    int idx = blockIdx.x * 256 + threadIdx.x;
    if (idx < n) {
        float tv = tt[idx];
        float a = ht[idx] + tv;
        float b = hm[idx] + tv;
        vout[idx] = a > 0.f ? a : expm1f(a);
        mout[idx] = b > 0.f ? b : expm1f(b);
    }
}

// out[row][c] = act( sum_j scale*(adjA[row][j] (+ adjB[row][j])) * X[j][c] + bias[c] ), C=64
__global__ __launch_bounds__(64) void spmm_kernel(
    const float* __restrict__ adjA, const float* __restrict__ adjB, float scale,
    const float* __restrict__ X, const float* __restrict__ bias,
    float* __restrict__ out, int act) {
    const int row = blockIdx.x, t = threadIdx.x;
    __shared__ int idxs[128];
    __shared__ float wts[128];
    __shared__ int cnt;
    if (t == 0) cnt = 0;
    __syncthreads();
    const float* ar = adjA + (size_t)row * 1024;
    const float* br = adjB ? adjB + (size_t)row * 1024 : nullptr;
    for (int j = t; j < 1024; j += 64) {
        float w = ar[j];
        if (br) w += br[j];
        if (w != 0.f) {
            int s = atomicAdd(&cnt, 1);
            if (s < 128) { idxs[s] = j; wts[s] = w * scale; }
        }
    }
    __syncthreads();
    int n = cnt < 128 ? cnt : 128;
    float acc = bias ? bias[t] : 0.f;
    for (int k = 0; k < n; ++k) acc += wts[k] * X[(size_t)idxs[k] * 64 + t];
    if (act == ACT_RELU) acc = fmaxf(acc, 0.f);
    out[(size_t)row * 64 + t] = acc;
}

// in-place row L2 normalize, 64 cols, one wave per row
__global__ __launch_bounds__(64) void l2norm_kernel(float* __restrict__ X) {
    const int row = blockIdx.x, t = threadIdx.x;
    float v = X[(size_t)row * 64 + t];
    float s = v * v;
    #pragma unroll
    for (int o = 32; o; o >>= 1) s += __shfl_down(s, o);
    s = __shfl(s, 0);
    float nrm = fmaxf(sqrtf(s), 1e-12f);
    X[(size_t)row * 64 + t] = v / nrm;
}

// e_acc[v] += sum_c tanh( (hs[v][row] @ att_w)[c] + att_b[c] ) * att_vec[c]
__global__ __launch_bounds__(64) void att_kernel(
    const float* __restrict__ hs, const float* __restrict__ att_w,
    const float* __restrict__ att_b, const float* __restrict__ att_vec,
    float* __restrict__ e_acc) {
    const int row = blockIdx.x, v = blockIdx.y, t = threadIdx.x;
    __shared__ float rs[64];
    rs[t] = hs[((size_t)v * 1024 + row) * 64 + t];
    __syncthreads();
    float s = att_b[t];
    #pragma unroll
    for (int k = 0; k < 64; ++k) s += rs[k] * att_w[k * 64 + t];
    float val = tanhf(s) * att_vec[t];
    #pragma unroll
    for (int o = 32; o; o >>= 1) val += __shfl_down(val, o);
    if (t == 0) atomicAdd(&e_acc[v], val);
}

// small[0..3]=e_acc -> small[5..8]=softmax(e/1024)
__global__ void beta_kernel(float* __restrict__ small) {
    if (threadIdx.x == 0) {
        float e[4], mx = -1e30f;
        for (int v = 0; v < 4; ++v) { e[v] = small[v] * (1.f / 1024.f); mx = fmaxf(mx, e[v]); }
        float s = 0.f;
        for (int v = 0; v < 4; ++v) { e[v] = expf(e[v] - mx); s += e[v]; }
        for (int v = 0; v < 4; ++v) small[5 + v] = e[v] / s;
    }
}

__global__ void zfine_kernel(const float* __restrict__ hs, const float* __restrict__ small,
                             float* __restrict__ z_fine) {
    int idx = blockIdx.x * 256 + threadIdx.x;
    if (idx < 65536) {
        float b0 = small[5], b1 = small[6], b2 = small[7], b3 = small[8];
        z_fine[idx] = b0 * hs[idx] + b1 * hs[idx + 65536] +
                      b2 * hs[idx + 131072] + b3 * hs[idx + 196608];
    }
}

// per-row i: denom_i = sum_j exp(2*zf_i.zc_j) * sigmoid(sum_k tanh(A1_i+C1_j+b1)_k*m2_k + b2)
// loss_acc += log(denom_i) - 2*zf_i.zc_i
__global__ __launch_bounds__(256) void infonce_kernel(
    const float* __restrict__ zf, const float* __restrict__ zc,
    const float* __restrict__ A1, const float* __restrict__ C1,
    const float* __restrict__ b1, const float* __restrict__ m2,
    const float* __restrict__ b2v, float* __restrict__ loss_acc) {
    const int i = blockIdx.x, t = threadIdx.x;
    __shared__ __align__(16) float zfs[64];
    __shared__ float a1s[16], b1s[16], m2s[16];
    __shared__ float diag_s;
    __shared__ float wsum[4];
    if (t < 64) zfs[t] = zf[(size_t)i * 64 + t];
    if (t < 16) { a1s[t] = A1[(size_t)i * 16 + t]; b1s[t] = b1[t]; m2s[t] = m2[t]; }
    __syncthreads();
    const float b2 = b2v[0];
    float acc = 0.f;
    for (int j = t; j < 1024; j += 256) {
        const float4* zcj = reinterpret_cast<const float4*>(zc + (size_t)j * 64);
        const float4* zfs4 = reinterpret_cast<const float4*>(zfs);
        float dot = 0.f;
        #pragma unroll
        for (int e = 0; e < 16; ++e) {
            float4 a = zfs4[e], b = zcj[e];
            dot += a.x * b.x + a.y * b.y + a.z * b.z + a.w * b.w;
        }
        float logit = dot * 2.0f; // 1/TAU
        const float* c1j = C1 + (size_t)j * 16;
        float h = 0.f;
        #pragma unroll
        for (int k = 0; k < 16; ++k) h += tanhf(a1s[k] + c1j[k] + b1s[k]) * m2s[k];
        float w = 1.f / (1.f + expf(-(h + b2)));
        acc += expf(logit) * w;
        if (j == i) diag_s = logit;
    }
    #pragma unroll
    for (int o = 32; o; o >>= 1) acc += __shfl_down(acc, o);
    if ((t & 63) == 0) wsum[t >> 6] = acc;
    __syncthreads();
    if (t == 0) {
        float denom = wsum[0] + wsum[1] + wsum[2] + wsum[3];
        atomicAdd(loss_acc, logf(denom) - diag_s);
    }
}

__global__ void finalize_kernel(const float* __restrict__ small, float* __restrict__ out) {
    if (threadIdx.x == 0) out[0] = small[4] * (1.f / 1024.f);
}

extern "C" void kernel_launch(void* const* d_in, const int* in_sizes, int n_in,
                              void* d_out, int out_size, void* d_ws, size_t ws_size,
                              hipStream_t stream) {
    const float* feat0     = (const float*)d_in[0];
    const float* feat1     = (const float*)d_in[1];
    const float* feat2     = (const float*)d_in[2];
    const float* mask_feat = (const float*)d_in[3];
    const float* nei0      = (const float*)d_in[4];
    const float* nei1      = (const float*)d_in[5];
    const float* adj0      = (const float*)d_in[6];
    const float* adj1      = (const float*)d_in[7];
    const float* madj0     = (const float*)d_in[8];
    const float* madj1     = (const float*)d_in[9];
    const float* fc0_w = (const float*)d_in[10];
    const float* fc0_b = (const float*)d_in[11];
    const float* fc1_w = (const float*)d_in[12];
    const float* fc1_b = (const float*)d_in[13];
    const float* fc2_w = (const float*)d_in[14];
    const float* fc2_b = (const float*)d_in[15];
    const float* agg0_w = (const float*)d_in[16];
    const float* agg1_w = (const float*)d_in[17];
    const float* gcn_w1 = (const float*)d_in[18];
    const float* gcn_b1 = (const float*)d_in[19];
    const float* gcn_w2 = (const float*)d_in[20];
    const float* gcn_b2 = (const float*)d_in[21];
    const float* att_w  = (const float*)d_in[22];
    const float* att_b  = (const float*)d_in[23];
    const float* att_vec = (const float*)d_in[24];
    const float* proj_w = (const float*)d_in[25];
    const float* proj_b = (const float*)d_in[26];
    const float* mlp1_w = (const float*)d_in[27];
    const float* mlp1_b = (const float*)d_in[28];
    const float* mlp2_w = (const float*)d_in[29];
    const float* mlp2_b = (const float*)d_in[30];

    const int N = 1024, M = 4096, D0 = 1024, D1 = 512, H = 512, E = 64;

    float* W = (float*)d_ws;
    size_t off = 0;
    auto alloc = [&](size_t n) { float* p = W + off; off += n; return p; };
    float* h_tar   = alloc((size_t)N * H);
    float* h_mask  = alloc((size_t)N * H);
    float* h_nei0  = alloc((size_t)M * H);
    float* h_nei1  = alloc((size_t)M * H);
    float* h_agg   = alloc((size_t)N * H);
    float* tbuf    = alloc((size_t)N * H);
    float* views0  = alloc((size_t)N * H);
    float* views1  = alloc((size_t)N * H);
    float* masks0  = alloc((size_t)N * H);
    float* masks1  = alloc((size_t)N * H);
    float* xw1     = alloc((size_t)N * E);
    float* h1      = alloc((size_t)N * E);
    float* hw2     = alloc((size_t)N * E);
    float* z_coarse= alloc((size_t)N * E);
    float* hs      = alloc((size_t)4 * N * E);
    float* z_fine  = alloc((size_t)N * E);
    float* zc      = alloc((size_t)N * E);
    float* zf      = alloc((size_t)N * E);
    float* A1      = alloc((size_t)N * 16);
    float* C1      = alloc((size_t)N * 16);
    float* small   = alloc(16); // [0..3]=e_acc [4]=loss_acc [5..8]=beta

    auto gemm = [&](const float* A, const float* B, const float* bias, float* C,
                    int Mm, int Kk, int Nn, int act) {
        dim3 g((Nn + 63) / 64, (Mm + 63) / 64);
        gemm_kernel<<<g, 256, 0, stream>>>(A, B, bias, C, Mm, Kk, Nn, act);
    };
    auto spmm = [&](const float* aA, const float* aB, float scale, const float* X,
                    const float* bias, float* out, int act) {
        spmm_kernel<<<N, 64, 0, stream>>>(aA, aB, scale, X, bias, out, act);
    };
    auto gcn = [&](const float* x, const float* aA, const float* aB, float scale, float* out) {
        gemm(x, gcn_w1, nullptr, xw1, N, H, E, ACT_NONE);
        spmm(aA, aB, scale, xw1, gcn_b1, h1, ACT_RELU);
        gemm(h1, gcn_w2, nullptr, hw2, N, E, E, ACT_NONE);
        spmm(aA, aB, scale, hw2, gcn_b2, out, ACT_NONE);
    };

    // zero accumulators (ws is poisoned each call)
    hipMemsetAsync((void*)small, 0, 16 * sizeof(float), stream);

    // projections + ELU
    gemm(feat0,     fc0_w, fc0_b, h_tar,  N, D0, H, ACT_ELU);
    gemm(mask_feat, fc0_w, fc0_b, h_mask, N, D0, H, ACT_ELU);
    gemm(feat1,     fc1_w, fc1_b, h_nei0, M, D1, H, ACT_ELU);
    gemm(feat2,     fc2_w, fc2_b, h_nei1, M, D1, H, ACT_ELU);

    // meta-path aggregation i=0
    neiagg_kernel<<<N, 256, 0, stream>>>(nei0, h_nei0, h_agg);
    gemm(h_agg, agg0_w, nullptr, tbuf, N, H, H, ACT_NONE);
    addelu_kernel<<<(N * H + 255) / 256, 256, 0, stream>>>(h_tar, h_mask, tbuf, views0, masks0, N * H);
    // i=1
    neiagg_kernel<<<N, 256, 0, stream>>>(nei1, h_nei1, h_agg);
    gemm(h_agg, agg1_w, nullptr, tbuf, N, H, H, ACT_NONE);
    addelu_kernel<<<(N * H + 255) / 256, 256, 0, stream>>>(h_tar, h_mask, tbuf, views1, masks1, N * H);

    // GCNs
    gcn(h_tar, adj0, adj1, 0.5f, z_coarse);
    gcn(views0, adj0, nullptr, 1.f, hs + 0 * (size_t)N * E);
    gcn(masks0, madj0, nullptr, 1.f, hs + 1 * (size_t)N * E);
    gcn(views1, adj1, nullptr, 1.f, hs + 2 * (size_t)N * E);
    gcn(masks1, madj1, nullptr, 1.f, hs + 3 * (size_t)N * E);

    // l2norm all 4 fine views in place ([4N, E])
    l2norm_kernel<<<4 * N, 64, 0, stream>>>(hs);

    // semantic attention
    att_kernel<<<dim3(N, 4), 64, 0, stream>>>(hs, att_w, att_b, att_vec, small);
    beta_kernel<<<1, 64, 0, stream>>>(small);
    zfine_kernel<<<(N * E + 255) / 256, 256, 0, stream>>>(hs, small, z_fine);

    // projection head + normalize
    gemm(z_coarse, proj_w, proj_b, zc, N, E, E, ACT_TANH);
    gemm(z_fine,   proj_w, proj_b, zf, N, E, E, ACT_TANH);
    l2norm_kernel<<<N, 64, 0, stream>>>(zc);
    l2norm_kernel<<<N, 64, 0, stream>>>(zf);

    // InfoNCE: precompute linear parts of pair MLP
    gemm(zf, mlp1_w, nullptr, A1, N, E, 16, ACT_NONE);
    gemm(zc, mlp1_w, nullptr, C1, N, E, 16, ACT_NONE);
    infonce_kernel<<<N, 256, 0, stream>>>(zf, zc, A1, C1, mlp1_b, mlp2_w, mlp2_b, small + 4);

    finalize_kernel<<<1, 64, 0, stream>>>(small, (float*)d_out);
}

// Round 2
// 487.116 us; speedup vs baseline: 1.9645x; 1.9645x over previous
//
#include <hip/hip_runtime.h>

#define ACT_NONE 0
#define ACT_ELU  1
#define ACT_RELU 2
#define ACT_TANH 3

typedef __attribute__((ext_vector_type(8))) short short8;
typedef __attribute__((ext_vector_type(4))) float f32x4;

__device__ __forceinline__ float apply_act(float v, int act) {
    if (act == ACT_ELU)  return v > 0.f ? v : expm1f(v);
    if (act == ACT_RELU) return fmaxf(v, 0.f);
    if (act == ACT_TANH) return tanhf(v);
    return v;
}

__device__ __forceinline__ unsigned short f2bf(float f) {
    unsigned int u = __float_as_uint(f);
    unsigned int r = (u + 0x7fffu + ((u >> 16) & 1u)) >> 16;
    return (unsigned short)r;
}

// ---------------- casts ----------------
// elementwise fp32 -> bf16, n % 4 == 0
__global__ __launch_bounds__(256) void cast_kernel(const float* __restrict__ in,
                                                   unsigned short* __restrict__ out, int n) {
    int i = (blockIdx.x * 256 + threadIdx.x) * 4;
    if (i < n) {
        float4 v = *reinterpret_cast<const float4*>(&in[i]);
        ushort4 o;
        o.x = f2bf(v.x); o.y = f2bf(v.y); o.z = f2bf(v.z); o.w = f2bf(v.w);
        *reinterpret_cast<ushort4*>(&out[i]) = o;
    }
}

// transpose + cast: in [R,C] fp32 -> out [C,R] bf16
__global__ void castT_kernel(const float* __restrict__ in, unsigned short* __restrict__ out,
                             int R, int C) {
    __shared__ float t[32][33];
    int r0 = blockIdx.y * 32, c0 = blockIdx.x * 32;
    int tx = threadIdx.x, ty = threadIdx.y; // 32 x 8
    for (int i = ty; i < 32; i += 8) {
        int r = r0 + i, c = c0 + tx;
        t[i][tx] = (r < R && c < C) ? in[(size_t)r * C + c] : 0.f;
    }
    __syncthreads();
    for (int i = ty; i < 32; i += 8) {
        int c = c0 + i, r = r0 + tx;
        if (c < C && r < R) out[(size_t)c * R + r] = f2bf(t[tx][i]);
    }
}

// ---------------- MFMA GEMM ----------------
// C[M,N] = act(A[M,K] @ B[K,N] + bias); A bf16 [M,K], Bt bf16 [N,K] (pre-transposed).
// Requires M%64==0, K%32==0. N arbitrary (guarded). No LDS: frags straight from L2.
// Block 256 thr = 4 waves (2x2), 64x64 tile, each wave 32x32 (2x2 16x16 frags).
__global__ __launch_bounds__(256) void gemm_bf16_kernel(
    const unsigned short* __restrict__ A, const unsigned short* __restrict__ Bt,
    const float* __restrict__ bias, float* __restrict__ C,
    int M, int K, int N, int act) {
    const int tid = threadIdx.x;
    const int w = tid >> 6, lane = tid & 63;
    const int wr = w >> 1, wc = w & 1;
    const int lr = lane & 15, lk = lane >> 4;
    const int bm = blockIdx.y * 64, bn = blockIdx.x * 64;

    const int arow0 = bm + wr * 32 + lr;
    const int brow0 = bn + wc * 32 + lr;

    f32x4 acc[2][2] = {};
    const short8 zero8 = {};
    #pragma unroll 4
    for (int k0 = 0; k0 < K; k0 += 32) {
        short8 a[2], b[2];
        #pragma unroll
        for (int i = 0; i < 2; ++i)
            a[i] = *reinterpret_cast<const short8*>(&A[(size_t)(arow0 + i * 16) * K + k0 + lk * 8]);
        #pragma unroll
        for (int j = 0; j < 2; ++j) {
            int br = brow0 + j * 16;
            b[j] = (br < N) ? *reinterpret_cast<const short8*>(&Bt[(size_t)br * K + k0 + lk * 8])
                            : zero8;
        }
        #pragma unroll
        for (int i = 0; i < 2; ++i)
            #pragma unroll
            for (int j = 0; j < 2; ++j)
                acc[i][j] = __builtin_amdgcn_mfma_f32_16x16x32_bf16(a[i], b[j], acc[i][j], 0, 0, 0);
    }
    #pragma unroll
    for (int i = 0; i < 2; ++i) {
        #pragma unroll
        for (int j = 0; j < 2; ++j) {
            int gcol = bn + wc * 32 + j * 16 + lr;
            if (gcol >= N) continue;
            float bv = bias ? bias[gcol] : 0.f;
            #pragma unroll
            for (int r = 0; r < 4; ++r) {
                int grow = bm + wr * 32 + i * 16 + lk * 4 + r;
                C[(size_t)grow * N + gcol] = apply_act(acc[i][j][r] + bv, act);
            }
        }
    }
}

// ---------------- sparse ops ----------------
// h_agg_bf[row] = bf16( (sum_{j: nei[row][j]!=0} h_nei[j]) / max(count,1) )
__global__ __launch_bounds__(256) void neiagg_kernel(
    const float* __restrict__ nei, const float* __restrict__ hn,
    unsigned short* __restrict__ hagg) {
    const int row = blockIdx.x, t = threadIdx.x;
    __shared__ int idxs[256];
    __shared__ int cnt;
    if (t == 0) cnt = 0;
    __syncthreads();
    const float4* nr = reinterpret_cast<const float4*>(nei + (size_t)row * 4096);
    for (int j = t; j < 1024; j += 256) {
        float4 v = nr[j];
        if (v.x != 0.f) { int s = atomicAdd(&cnt, 1); if (s < 256) idxs[s] = j * 4 + 0; }
        if (v.y != 0.f) { int s = atomicAdd(&cnt, 1); if (s < 256) idxs[s] = j * 4 + 1; }
        if (v.z != 0.f) { int s = atomicAdd(&cnt, 1); if (s < 256) idxs[s] = j * 4 + 2; }
        if (v.w != 0.f) { int s = atomicAdd(&cnt, 1); if (s < 256) idxs[s] = j * 4 + 3; }
    }
    __syncthreads();
    int n = cnt < 256 ? cnt : 256;
    float inv = 1.f / fmaxf((float)cnt, 1.f);
    for (int c = t; c < 512; c += 256) {
        float acc = 0.f;
        for (int k = 0; k < n; ++k) acc += hn[(size_t)idxs[k] * 512 + c];
        hagg[(size_t)row * 512 + c] = f2bf(acc * inv);
    }
}

// views/masks = elu(h +/- t), written as bf16 into xcat branches
__global__ void addelu_kernel(const float* __restrict__ ht, const float* __restrict__ hm,
                              const float* __restrict__ tt, unsigned short* __restrict__ vout,
                              unsigned short* __restrict__ mout, int n) {
    int idx = blockIdx.x * 256 + threadIdx.x;
    if (idx < n) {
        float tv = tt[idx];
        float a = ht[idx] + tv;
        float b = hm[idx] + tv;
        vout[idx] = f2bf(a > 0.f ? a : expm1f(a));
        mout[idx] = f2bf(b > 0.f ? b : expm1f(b));
    }
}

// branch br: out[br] = relu(adj_br @ X[br] + b1) as bf16.  X [5][1024][64]
__global__ __launch_bounds__(64) void spmm1_kernel(
    const float* __restrict__ adj0, const float* __restrict__ adj1,
    const float* __restrict__ madj0, const float* __restrict__ madj1,
    const float* __restrict__ X, const float* __restrict__ bias,
    unsigned short* __restrict__ out) {
    const int row = blockIdx.x, br = blockIdx.y, t = threadIdx.x;
    const float* Aa; const float* Ab = nullptr; float sc = 1.f;
    if (br == 0)      { Aa = adj0; Ab = adj1; sc = 0.5f; }
    else if (br == 1) { Aa = adj0; }
    else if (br == 2) { Aa = madj0; }
    else if (br == 3) { Aa = adj1; }
    else              { Aa = madj1; }
    __shared__ int idxs[128];
    __shared__ float wts[128];
    __shared__ int cnt;
    if (t == 0) cnt = 0;
    __syncthreads();
    const float4* ar = reinterpret_cast<const float4*>(Aa + (size_t)row * 1024);
    const float4* brp = Ab ? reinterpret_cast<const float4*>(Ab + (size_t)row * 1024) : nullptr;
    for (int j = t; j < 256; j += 64) {
        float4 v = ar[j];
        if (brp) { float4 u = brp[j]; v.x += u.x; v.y += u.y; v.z += u.z; v.w += u.w; }
        if (v.x != 0.f) { int s = atomicAdd(&cnt, 1); if (s < 128) { idxs[s] = j * 4 + 0; wts[s] = v.x * sc; } }
        if (v.y != 0.f) { int s = atomicAdd(&cnt, 1); if (s < 128) { idxs[s] = j * 4 + 1; wts[s] = v.y * sc; } }
        if (v.z != 0.f) { int s = atomicAdd(&cnt, 1); if (s < 128) { idxs[s] = j * 4 + 2; wts[s] = v.z * sc; } }
        if (v.w != 0.f) { int s = atomicAdd(&cnt, 1); if (s < 128) { idxs[s] = j * 4 + 3; wts[s] = v.w * sc; } }
    }
    __syncthreads();
    int n = cnt < 128 ? cnt : 128;
    float acc = bias[t];
    const float* Xb = X + (size_t)br * 1024 * 64;
    for (int k = 0; k < n; ++k) acc += wts[k] * Xb[(size_t)idxs[k] * 64 + t];
    out[((size_t)br * 1024 + row) * 64 + t] = f2bf(fmaxf(acc, 0.f));
}

// branch 0 -> zcf (no norm); branches 1..4 -> hs[br-1] with fused row-l2norm
__global__ __launch_bounds__(64) void spmm2_kernel(
    const float* __restrict__ adj0, const float* __restrict__ adj1,
    const float* __restrict__ madj0, const float* __restrict__ madj1,
    const float* __restrict__ X, const float* __restrict__ bias,
    float* __restrict__ zcf, float* __restrict__ hs) {
    const int row = blockIdx.x, br = blockIdx.y, t = threadIdx.x;
    const float* Aa; const float* Ab = nullptr; float sc = 1.f;
    if (br == 0)      { Aa = adj0; Ab = adj1; sc = 0.5f; }
    else if (br == 1) { Aa = adj0; }
    else if (br == 2) { Aa = madj0; }
    else if (br == 3) { Aa = adj1; }
    else              { Aa = madj1; }
    __shared__ int idxs[128];
    __shared__ float wts[128];
    __shared__ int cnt;
    if (t == 0) cnt = 0;
    __syncthreads();
    const float4* ar = reinterpret_cast<const float4*>(Aa + (size_t)row * 1024);
    const float4* brp = Ab ? reinterpret_cast<const float4*>(Ab + (size_t)row * 1024) : nullptr;
    for (int j = t; j < 256; j += 64) {
        float4 v = ar[j];
        if (brp) { float4 u = brp[j]; v.x += u.x; v.y += u.y; v.z += u.z; v.w += u.w; }
        if (v.x != 0.f) { int s = atomicAdd(&cnt, 1); if (s < 128) { idxs[s] = j * 4 + 0; wts[s] = v.x * sc; } }
        if (v.y != 0.f) { int s = atomicAdd(&cnt, 1); if (s < 128) { idxs[s] = j * 4 + 1; wts[s] = v.y * sc; } }
        if (v.z != 0.f) { int s = atomicAdd(&cnt, 1); if (s < 128) { idxs[s] = j * 4 + 2; wts[s] = v.z * sc; } }
        if (v.w != 0.f) { int s = atomicAdd(&cnt, 1); if (s < 128) { idxs[s] = j * 4 + 3; wts[s] = v.w * sc; } }
    }
    __syncthreads();
    int n = cnt < 128 ? cnt : 128;
    float acc = bias[t];
    const float* Xb = X + (size_t)br * 1024 * 64;
    for (int k = 0; k < n; ++k) acc += wts[k] * Xb[(size_t)idxs[k] * 64 + t];
    if (br == 0) {
        zcf[(size_t)row * 64 + t] = acc;
    } else {
        float s = acc * acc;
        #pragma unroll
        for (int o = 32; o; o >>= 1) s += __shfl_down(s, o);
        s = __shfl(s, 0);
        float nrm = fmaxf(sqrtf(s), 1e-12f);
        hs[((size_t)(br - 1) * 1024 + row) * 64 + t] = acc / nrm;
    }
}

// in-place row L2 normalize, 64 cols, one wave per row
__global__ __launch_bounds__(64) void l2norm_kernel(float* __restrict__ X) {
    const int row = blockIdx.x, t = threadIdx.x;
    float v = X[(size_t)row * 64 + t];
    float s = v * v;
    #pragma unroll
    for (int o = 32; o; o >>= 1) s += __shfl_down(s, o);
    s = __shfl(s, 0);
    float nrm = fmaxf(sqrtf(s), 1e-12f);
    X[(size_t)row * 64 + t] = v / nrm;
}

// e_acc[v] += sum_c tanh( (hs[v][row] @ att_w)[c] + att_b[c] ) * att_vec[c]
__global__ __launch_bounds__(64) void att_kernel(
    const float* __restrict__ hs, const float* __restrict__ att_w,
    const float* __restrict__ att_b, const float* __restrict__ att_vec,
    float* __restrict__ e_acc) {
    const int row = blockIdx.x, v = blockIdx.y, t = threadIdx.x;
    __shared__ float rs[64];
    rs[t] = hs[((size_t)v * 1024 + row) * 64 + t];
    __syncthreads();
    float s = att_b[t];
    #pragma unroll
    for (int k = 0; k < 64; ++k) s += rs[k] * att_w[k * 64 + t];
    float val = tanhf(s) * att_vec[t];
    #pragma unroll
    for (int o = 32; o; o >>= 1) val += __shfl_down(val, o);
    if (t == 0) atomicAdd(&e_acc[v], val);
}

__global__ void beta_kernel(float* __restrict__ small) {
    if (threadIdx.x == 0) {
        float e[4], mx = -1e30f;
        for (int v = 0; v < 4; ++v) { e[v] = small[v] * (1.f / 1024.f); mx = fmaxf(mx, e[v]); }
        float s = 0.f;
        for (int v = 0; v < 4; ++v) { e[v] = expf(e[v] - mx); s += e[v]; }
        for (int v = 0; v < 4; ++v) small[5 + v] = e[v] / s;
    }
}

// z_fine (into zcf + 65536)
__global__ void zfine_kernel(const float* __restrict__ hs, const float* __restrict__ small,
                             float* __restrict__ z_fine) {
    int idx = blockIdx.x * 256 + threadIdx.x;
    if (idx < 65536) {
        float b0 = small[5], b1 = small[6], b2 = small[7], b3 = small[8];
        z_fine[idx] = b0 * hs[idx] + b1 * hs[idx + 65536] +
                      b2 * hs[idx + 131072] + b3 * hs[idx + 196608];
    }
}

__global__ __launch_bounds__(256) void infonce_kernel(
    const float* __restrict__ zf, const float* __restrict__ zc,
    const float* __restrict__ A1, const float* __restrict__ C1,
    const float* __restrict__ b1, const float* __restrict__ m2,
    const float* __restrict__ b2v, float* __restrict__ loss_acc) {
    const int i = blockIdx.x, t = threadIdx.x;
    __shared__ __align__(16) float zfs[64];
    __shared__ float a1s[16], b1s[16], m2s[16];
    __shared__ float diag_s;
    __shared__ float wsum[4];
    if (t < 64) zfs[t] = zf[(size_t)i * 64 + t];
    if (t < 16) { a1s[t] = A1[(size_t)i * 16 + t]; b1s[t] = b1[t]; m2s[t] = m2[t]; }
    __syncthreads();
    const float b2 = b2v[0];
    float acc = 0.f;
    for (int j = t; j < 1024; j += 256) {
        const float4* zcj = reinterpret_cast<const float4*>(zc + (size_t)j * 64);
        const float4* zfs4 = reinterpret_cast<const float4*>(zfs);
        float dot = 0.f;
        #pragma unroll
        for (int e = 0; e < 16; ++e) {
            float4 a = zfs4[e], b = zcj[e];
            dot += a.x * b.x + a.y * b.y + a.z * b.z + a.w * b.w;
        }
        float logit = dot * 2.0f; // 1/TAU
        const float* c1j = C1 + (size_t)j * 16;
        float h = 0.f;
        #pragma unroll
        for (int k = 0; k < 16; ++k) h += tanhf(a1s[k] + c1j[k] + b1s[k]) * m2s[k];
        float w = 1.f / (1.f + expf(-(h + b2)));
        acc += expf(logit) * w;
        if (j == i) diag_s = logit;
    }
    #pragma unroll
    for (int o = 32; o; o >>= 1) acc += __shfl_down(acc, o);
    if ((t & 63) == 0) wsum[t >> 6] = acc;
    __syncthreads();
    if (t == 0) {
        float denom = wsum[0] + wsum[1] + wsum[2] + wsum[3];
        atomicAdd(loss_acc, logf(denom) - diag_s);
    }
}

__global__ void finalize_kernel(const float* __restrict__ small, float* __restrict__ out) {
    if (threadIdx.x == 0) out[0] = small[4] * (1.f / 1024.f);
}

extern "C" void kernel_launch(void* const* d_in, const int* in_sizes, int n_in,
                              void* d_out, int out_size, void* d_ws, size_t ws_size,
                              hipStream_t stream) {
    const float* feat0     = (const float*)d_in[0];
    const float* feat1     = (const float*)d_in[1];
    const float* feat2     = (const float*)d_in[2];
    const float* mask_feat = (const float*)d_in[3];
    const float* nei0      = (const float*)d_in[4];
    const float* nei1      = (const float*)d_in[5];
    const float* adj0      = (const float*)d_in[6];
    const float* adj1      = (const float*)d_in[7];
    const float* madj0     = (const float*)d_in[8];
    const float* madj1     = (const float*)d_in[9];
    const float* fc0_w = (const float*)d_in[10];
    const float* fc0_b = (const float*)d_in[11];
    const float* fc1_w = (const float*)d_in[12];
    const float* fc1_b = (const float*)d_in[13];
    const float* fc2_w = (const float*)d_in[14];
    const float* fc2_b = (const float*)d_in[15];
    const float* agg0_w = (const float*)d_in[16];
    const float* agg1_w = (const float*)d_in[17];
    const float* gcn_w1 = (const float*)d_in[18];
    const float* gcn_b1 = (const float*)d_in[19];
    const float* gcn_w2 = (const float*)d_in[20];
    const float* gcn_b2 = (const float*)d_in[21];
    const float* att_w  = (const float*)d_in[22];
    const float* att_b  = (const float*)d_in[23];
    const float* att_vec = (const float*)d_in[24];
    const float* proj_w = (const float*)d_in[25];
    const float* proj_b = (const float*)d_in[26];
    const float* mlp1_w = (const float*)d_in[27];
    const float* mlp1_b = (const float*)d_in[28];
    const float* mlp2_w = (const float*)d_in[29];
    const float* mlp2_b = (const float*)d_in[30];

    const int N = 1024, M = 4096, D0 = 1024, D1 = 512, H = 512, E = 64;
    typedef unsigned short bf;

    // ---- workspace layout ----
    float* W = (float*)d_ws;
    size_t off = 0;
    auto allocf = [&](size_t n) { float* p = W + off; off += n; return p; };
    float* h_tar   = allocf((size_t)N * H);        // 512K
    float* h_mask  = allocf((size_t)N * H);
    float* h_nei0  = allocf((size_t)M * H);        // 2M
    float* h_nei1  = allocf((size_t)M * H);
    float* tbuf    = allocf((size_t)N * H);
    float* xw1cat  = allocf((size_t)5 * N * E);    // 320K
    float* hw2cat  = allocf((size_t)5 * N * E);
    float* hs      = allocf((size_t)4 * N * E);    // 256K
    float* zcf     = allocf((size_t)2 * N * E);    // z_coarse | z_fine
    float* zcat    = allocf((size_t)2 * N * E);    // zc | zf
    float* AC1     = allocf((size_t)2 * N * 16);   // C1 | A1
    float* small   = allocf(16);
    // bf16 pool (2-byte elems) after fp32 pool
    bf* BP = (bf*)(W + off);
    size_t boff = 0;
    auto allocb = [&](size_t n) { bf* p = BP + boff; boff += n; return p; };
    bf* bfA      = allocb((size_t)6 * 1024 * 1024); // feat casts; later reused as xcat
    bf* feat0_bf = bfA;
    bf* mask_bf  = bfA + (size_t)1024 * 1024;
    bf* feat1_bf = bfA + (size_t)2 * 1024 * 1024;
    bf* feat2_bf = bfA + (size_t)4 * 1024 * 1024;
    bf* xcat_bf  = bfA;                             // [5][1024][512], alias (safe: used after)
    bf* hagg_bf  = allocb((size_t)N * H);
    bf* h1cat_bf = allocb((size_t)5 * N * E);
    bf* zcf_bf   = allocb((size_t)2 * N * E);
    bf* zcat_bf  = allocb((size_t)2 * N * E);
    bf* wT       = allocb((size_t)(512 * 1024 + 4 * 512 * 512 + 64 * 512 + 3 * 64 * 64));
    bf* fc0_wT  = wT;                                  // [512,1024]
    bf* fc1_wT  = fc0_wT + (size_t)512 * 1024;         // [512,512]
    bf* fc2_wT  = fc1_wT + (size_t)512 * 512;
    bf* agg0_wT = fc2_wT + (size_t)512 * 512;
    bf* agg1_wT = agg0_wT + (size_t)512 * 512;
    bf* gw1_T   = agg1_wT + (size_t)512 * 512;         // [64,512]
    bf* gw2_T   = gw1_T + (size_t)64 * 512;            // [64,64]
    bf* proj_wT = gw2_T + (size_t)64 * 64;
    bf* mlp1_wT = proj_wT + (size_t)64 * 64;           // [16,64]

    auto gemm = [&](const bf* A, const bf* Bt, const float* bias, float* C,
                    int Mm, int Kk, int Nn, int act) {
        dim3 g((Nn + 63) / 64, Mm / 64);
        gemm_bf16_kernel<<<g, 256, 0, stream>>>(A, Bt, bias, C, Mm, Kk, Nn, act);
    };
    auto castT = [&](const float* in, bf* out, int R, int C) {
        castT_kernel<<<dim3((C + 31) / 32, (R + 31) / 32), dim3(32, 8), 0, stream>>>(in, out, R, C);
    };
    auto cast = [&](const float* in, bf* out, int n) {
        cast_kernel<<<(n / 4 + 255) / 256, 256, 0, stream>>>(in, out, n);
    };

    hipMemsetAsync((void*)small, 0, 16 * sizeof(float), stream);

    // weight transposes (tiny)
    castT(fc0_w, fc0_wT, D0, H);
    castT(fc1_w, fc1_wT, D1, H);
    castT(fc2_w, fc2_wT, D1, H);
    castT(agg0_w, agg0_wT, H, H);
    castT(agg1_w, agg1_wT, H, H);
    castT(gcn_w1, gw1_T, H, E);
    castT(gcn_w2, gw2_T, E, E);
    castT(proj_w, proj_wT, E, E);
    castT(mlp1_w, mlp1_wT, E, 16);
    // input casts
    cast(feat0, feat0_bf, N * D0);
    cast(mask_feat, mask_bf, N * D0);
    cast(feat1, feat1_bf, M * D1);
    cast(feat2, feat2_bf, M * D1);

    // projections + ELU
    gemm(feat0_bf, fc0_wT, fc0_b, h_tar,  N, D0, H, ACT_ELU);
    gemm(mask_bf,  fc0_wT, fc0_b, h_mask, N, D0, H, ACT_ELU);
    gemm(feat1_bf, fc1_wT, fc1_b, h_nei0, M, D1, H, ACT_ELU);
    gemm(feat2_bf, fc2_wT, fc2_b, h_nei1, M, D1, H, ACT_ELU);

    // xcat branch 0 = h_tar (bf16)
    cast(h_tar, xcat_bf, N * H);
    // meta-path i=0 -> branches 1 (views0), 2 (masks0)
    neiagg_kernel<<<N, 256, 0, stream>>>(nei0, h_nei0, hagg_bf);
    gemm(hagg_bf, agg0_wT, nullptr, tbuf, N, H, H, ACT_NONE);
    addelu_kernel<<<(N * H + 255) / 256, 256, 0, stream>>>(
        h_tar, h_mask, tbuf, xcat_bf + (size_t)1 * N * H, xcat_bf + (size_t)2 * N * H, N * H);
    // i=1 -> branches 3 (views1), 4 (masks1)
    neiagg_kernel<<<N, 256, 0, stream>>>(nei1, h_nei1, hagg_bf);
    gemm(hagg_bf, agg1_wT, nullptr, tbuf, N, H, H, ACT_NONE);
    addelu_kernel<<<(N * H + 255) / 256, 256, 0, stream>>>(
        h_tar, h_mask, tbuf, xcat_bf + (size_t)3 * N * H, xcat_bf + (size_t)4 * N * H, N * H);

    // batched GCN: [5120,512]@[512,64] -> spmm(relu,bf16) -> [5120,64]@[64,64] -> spmm(+l2norm)
    gemm(xcat_bf, gw1_T, nullptr, xw1cat, 5 * N, H, E, ACT_NONE);
    spmm1_kernel<<<dim3(N, 5), 64, 0, stream>>>(adj0, adj1, madj0, madj1, xw1cat, gcn_b1, h1cat_bf);
    gemm(h1cat_bf, gw2_T, nullptr, hw2cat, 5 * N, E, E, ACT_NONE);
    spmm2_kernel<<<dim3(N, 5), 64, 0, stream>>>(adj0, adj1, madj0, madj1, hw2cat, gcn_b2, zcf, hs);

    // semantic attention -> z_fine (second half of zcf)
    att_kernel<<<dim3(N, 4), 64, 0, stream>>>(hs, att_w, att_b, att_vec, small);
    beta_kernel<<<1, 64, 0, stream>>>(small);
    zfine_kernel<<<(N * E + 255) / 256, 256, 0, stream>>>(hs, small, zcf + (size_t)N * E);

    // projection head: zcat = tanh([z_coarse; z_fine] @ proj_w + b), then l2norm
    cast(zcf, zcf_bf, 2 * N * E);
    gemm(zcf_bf, proj_wT, proj_b, zcat, 2 * N, E, E, ACT_TANH);
    l2norm_kernel<<<2 * N, 64, 0, stream>>>(zcat);

    // InfoNCE: AC1 = [C1; A1] = zcat @ mlp1_w
    cast(zcat, zcat_bf, 2 * N * E);
    gemm(zcat_bf, mlp1_wT, nullptr, AC1, 2 * N, E, 16, ACT_NONE);
    const float* zc = zcat;
    const float* zf = zcat + (size_t)N * E;
    const float* C1 = AC1;
    const float* A1 = AC1 + (size_t)N * 16;
    infonce_kernel<<<N, 256, 0, stream>>>(zf, zc, A1, C1, mlp1_b, mlp2_w, mlp2_b, small + 4);

    finalize_kernel<<<1, 64, 0, stream>>>(small, (float*)d_out);
}

// Round 3
// 383.800 us; speedup vs baseline: 2.4934x; 1.2692x over previous
//
#include <hip/hip_runtime.h>

#define ACT_NONE 0
#define ACT_ELU  1
#define ACT_RELU 2
#define ACT_TANH 3

typedef __attribute__((ext_vector_type(8))) short short8;
typedef __attribute__((ext_vector_type(4))) float f32x4;

__device__ __forceinline__ float frcp(float x) { return __builtin_amdgcn_rcpf(x); }
__device__ __forceinline__ float fexp(float x) { return __expf(x); }
// safe fast tanh: 1 - 2/(e^2x + 1). x=+inf -> 1, x=-inf -> -1, no NaN.
__device__ __forceinline__ float ftanh(float x) {
    return 1.f - 2.f * frcp(fexp(2.f * x) + 1.f);
}
__device__ __forceinline__ float fsigmoid(float x) {
    return frcp(1.f + fexp(-x));
}

__device__ __forceinline__ float apply_act(float v, int act) {
    if (act == ACT_ELU)  return v > 0.f ? v : fexp(v) - 1.f;
    if (act == ACT_RELU) return fmaxf(v, 0.f);
    if (act == ACT_TANH) return ftanh(v);
    return v;
}

__device__ __forceinline__ unsigned short f2bf(float f) {
    unsigned int u = __float_as_uint(f);
    unsigned int r = (u + 0x7fffu + ((u >> 16) & 1u)) >> 16;
    return (unsigned short)r;
}
__device__ __forceinline__ float bf2f(unsigned short u) {
    return __uint_as_float(((unsigned int)u) << 16);
}

// ---------------- batched casts ----------------
struct CMDesc { const float* in; unsigned short* out; int start4; };
struct CMArr { CMDesc d[6]; int n; int total4; };

__global__ __launch_bounds__(256) void cast_multi_kernel(CMArr a) {
    int g4 = blockIdx.x * 256 + threadIdx.x;
    if (g4 >= a.total4) return;
    int s = 0;
    while (s + 1 < a.n && g4 >= a.d[s + 1].start4) ++s;
    int l4 = g4 - a.d[s].start4;
    float4 v = *reinterpret_cast<const float4*>(a.d[s].in + (size_t)l4 * 4);
    ushort4 o;
    o.x = f2bf(v.x); o.y = f2bf(v.y); o.z = f2bf(v.z); o.w = f2bf(v.w);
    *reinterpret_cast<ushort4*>(a.d[s].out + (size_t)l4 * 4) = o;
}

struct CTDesc { const float* in; unsigned short* out; int R, C, tcols, tile0; };
struct CTArr { CTDesc d[10]; int n; };

__global__ void castT_multi_kernel(CTArr a) {
    int b = blockIdx.x, s = 0;
    while (s + 1 < a.n && b >= a.d[s + 1].tile0) ++s;
    const CTDesc d = a.d[s];
    int lt = b - d.tile0;
    int tr = lt / d.tcols, tc = lt % d.tcols;
    int r0 = tr * 32, c0 = tc * 32;
    __shared__ float t[32][33];
    int tx = threadIdx.x, ty = threadIdx.y; // 32 x 8
    for (int i = ty; i < 32; i += 8) {
        int r = r0 + i, c = c0 + tx;
        t[i][tx] = (r < d.R && c < d.C) ? d.in[(size_t)r * d.C + c] : 0.f;
    }
    __syncthreads();
    for (int i = ty; i < 32; i += 8) {
        int c = c0 + i, r = r0 + tx;
        if (c < d.C && r < d.R) d.out[(size_t)c * d.R + r] = f2bf(t[tx][i]);
    }
}

// ---------------- MFMA GEMM ----------------
// C[M,N] = act(A@B + bias); A bf16 [M,K], Bt bf16 [N,K] pre-transposed.
// Rows >= m_split use Bt2. Optional fp32 out C and/or bf16 out Cbf.
// M%64==0, K%32==0, N guarded.
__global__ __launch_bounds__(256) void gemm_bf16_kernel(
    const unsigned short* __restrict__ A, const unsigned short* __restrict__ Bt,
    const unsigned short* __restrict__ Bt2, int m_split,
    const float* __restrict__ bias, float* __restrict__ C,
    unsigned short* __restrict__ Cbf, int M, int K, int N, int act) {
    const int tid = threadIdx.x;
    const int w = tid >> 6, lane = tid & 63;
    const int wr = w >> 1, wc = w & 1;
    const int lr = lane & 15, lk = lane >> 4;
    const int bm = blockIdx.y * 64, bn = blockIdx.x * 64;
    const unsigned short* Bu = (bm >= m_split) ? Bt2 : Bt;

    const int arow0 = bm + wr * 32 + lr;
    const int brow0 = bn + wc * 32 + lr;

    f32x4 acc[2][2] = {};
    const short8 zero8 = {};
    #pragma unroll 4
    for (int k0 = 0; k0 < K; k0 += 32) {
        short8 a[2], b[2];
        #pragma unroll
        for (int i = 0; i < 2; ++i)
            a[i] = *reinterpret_cast<const short8*>(&A[(size_t)(arow0 + i * 16) * K + k0 + lk * 8]);
        #pragma unroll
        for (int j = 0; j < 2; ++j) {
            int br = brow0 + j * 16;
            b[j] = (br < N) ? *reinterpret_cast<const short8*>(&Bu[(size_t)br * K + k0 + lk * 8])
                            : zero8;
        }
        #pragma unroll
        for (int i = 0; i < 2; ++i)
            #pragma unroll
            for (int j = 0; j < 2; ++j)
                acc[i][j] = __builtin_amdgcn_mfma_f32_16x16x32_bf16(a[i], b[j], acc[i][j], 0, 0, 0);
    }
    #pragma unroll
    for (int i = 0; i < 2; ++i) {
        #pragma unroll
        for (int j = 0; j < 2; ++j) {
            int gcol = bn + wc * 32 + j * 16 + lr;
            if (gcol >= N) continue;
            float bv = bias ? bias[gcol] : 0.f;
            #pragma unroll
            for (int r = 0; r < 4; ++r) {
                int grow = bm + wr * 32 + i * 16 + lk * 4 + r;
                float v = apply_act(acc[i][j][r] + bv, act);
                if (C)   C[(size_t)grow * N + gcol] = v;
                if (Cbf) Cbf[(size_t)grow * N + gcol] = f2bf(v);
            }
        }
    }
}

// ---------------- sparse ops ----------------
// both meta-paths: hagg[br] = mean of bf16 h_nei rows selected by nei row
__global__ __launch_bounds__(256) void neiagg_kernel(
    const float* __restrict__ nei0, const float* __restrict__ nei1,
    const unsigned short* __restrict__ hn0, const unsigned short* __restrict__ hn1,
    unsigned short* __restrict__ hagg) {
    const int row = blockIdx.x, br = blockIdx.y, t = threadIdx.x;
    const float* nei = br ? nei1 : nei0;
    const unsigned short* hn = br ? hn1 : hn0;
    __shared__ int idxs[256];
    __shared__ int cnt;
    if (t == 0) cnt = 0;
    __syncthreads();
    const float4* nr = reinterpret_cast<const float4*>(nei + (size_t)row * 4096);
    for (int j = t; j < 1024; j += 256) {
        float4 v = nr[j];
        if (v.x != 0.f) { int s = atomicAdd(&cnt, 1); if (s < 256) idxs[s] = j * 4 + 0; }
        if (v.y != 0.f) { int s = atomicAdd(&cnt, 1); if (s < 256) idxs[s] = j * 4 + 1; }
        if (v.z != 0.f) { int s = atomicAdd(&cnt, 1); if (s < 256) idxs[s] = j * 4 + 2; }
        if (v.w != 0.f) { int s = atomicAdd(&cnt, 1); if (s < 256) idxs[s] = j * 4 + 3; }
    }
    __syncthreads();
    int n = cnt < 256 ? cnt : 256;
    float inv = frcp(fmaxf((float)cnt, 1.f));
    // 2 cols per thread
    int c = t * 2;
    float a0 = 0.f, a1 = 0.f;
    for (int k = 0; k < n; ++k) {
        ushort2 u = *reinterpret_cast<const ushort2*>(&hn[(size_t)idxs[k] * 512 + c]);
        a0 += bf2f(u.x); a1 += bf2f(u.y);
    }
    ushort2 o; o.x = f2bf(a0 * inv); o.y = f2bf(a1 * inv);
    *reinterpret_cast<ushort2*>(&hagg[((size_t)br * 1024 + row) * 512 + c]) = o;
}

// views/masks for both meta-paths -> xcat branches 1..4 (bf16)
__global__ void addelu_kernel(const float* __restrict__ ht, const float* __restrict__ hm,
                              const float* __restrict__ tt, unsigned short* __restrict__ xcat,
                              int nh) {
    int idx = blockIdx.x * 256 + threadIdx.x;
    if (idx < nh) {
        float h1 = ht[idx], h2 = hm[idx];
        float t0 = tt[idx], t1 = tt[idx + nh];
        float a = h1 + t0, b = h2 + t0, c = h1 + t1, d = h2 + t1;
        xcat[(size_t)1 * nh + idx] = f2bf(a > 0.f ? a : fexp(a) - 1.f);
        xcat[(size_t)2 * nh + idx] = f2bf(b > 0.f ? b : fexp(b) - 1.f);
        xcat[(size_t)3 * nh + idx] = f2bf(c > 0.f ? c : fexp(c) - 1.f);
        xcat[(size_t)4 * nh + idx] = f2bf(d > 0.f ? d : fexp(d) - 1.f);
    }
}

// scan adjacency rows once into compact lists. br0 = 0.5*(adj0+adj1), 1=adj0, 2=madj0, 3=adj1, 4=madj1
__global__ __launch_bounds__(64) void adjprep_kernel(
    const float* __restrict__ adj0, const float* __restrict__ adj1,
    const float* __restrict__ madj0, const float* __restrict__ madj1,
    int* __restrict__ cnts, int* __restrict__ idxs, float* __restrict__ wts) {
    const int row = blockIdx.x, br = blockIdx.y, t = threadIdx.x;
    const float* Aa; const float* Ab = nullptr; float sc = 1.f;
    if (br == 0)      { Aa = adj0; Ab = adj1; sc = 0.5f; }
    else if (br == 1) { Aa = adj0; }
    else if (br == 2) { Aa = madj0; }
    else if (br == 3) { Aa = adj1; }
    else              { Aa = madj1; }
    __shared__ int li[128];
    __shared__ float lw[128];
    __shared__ int cnt;
    if (t == 0) cnt = 0;
    __syncthreads();
    const float4* ar = reinterpret_cast<const float4*>(Aa + (size_t)row * 1024);
    const float4* brp = Ab ? reinterpret_cast<const float4*>(Ab + (size_t)row * 1024) : nullptr;
    for (int j = t; j < 256; j += 64) {
        float4 v = ar[j];
        if (brp) { float4 u = brp[j]; v.x += u.x; v.y += u.y; v.z += u.z; v.w += u.w; }
        if (v.x != 0.f) { int s = atomicAdd(&cnt, 1); if (s < 128) { li[s] = j * 4 + 0; lw[s] = v.x * sc; } }
        if (v.y != 0.f) { int s = atomicAdd(&cnt, 1); if (s < 128) { li[s] = j * 4 + 1; lw[s] = v.y * sc; } }
        if (v.z != 0.f) { int s = atomicAdd(&cnt, 1); if (s < 128) { li[s] = j * 4 + 2; lw[s] = v.z * sc; } }
        if (v.w != 0.f) { int s = atomicAdd(&cnt, 1); if (s < 128) { li[s] = j * 4 + 3; lw[s] = v.w * sc; } }
    }
    __syncthreads();
    int n = cnt < 128 ? cnt : 128;
    size_t base = ((size_t)br * 1024 + row) * 128;
    for (int k = t; k < n; k += 64) { idxs[base + k] = li[k]; wts[base + k] = lw[k]; }
    if (t == 0) cnts[br * 1024 + row] = n;
}

// h1cat[br] = bf16(relu(adj_br @ X[br] + b1)), X [5][1024][64] fp32
__global__ __launch_bounds__(64) void spmm1_kernel(
    const int* __restrict__ cnts, const int* __restrict__ idxs, const float* __restrict__ wts,
    const float* __restrict__ X, const float* __restrict__ bias,
    unsigned short* __restrict__ out) {
    const int row = blockIdx.x, br = blockIdx.y, t = threadIdx.x;
    size_t base = ((size_t)br * 1024 + row) * 128;
    int n = cnts[br * 1024 + row];
    float acc = bias[t];
    const float* Xb = X + (size_t)br * 1024 * 64;
    for (int k = 0; k < n; ++k)
        acc += wts[base + k] * Xb[(size_t)idxs[base + k] * 64 + t];
    out[((size_t)br * 1024 + row) * 64 + t] = f2bf(fmaxf(acc, 0.f));
}

// br0 -> zcf_bf (bf16, no norm); br1..4 -> hs[br-1] fp32 with fused l2norm + att partial
__global__ __launch_bounds__(64) void spmm2_kernel(
    const int* __restrict__ cnts, const int* __restrict__ idxs, const float* __restrict__ wts,
    const float* __restrict__ X, const float* __restrict__ bias,
    unsigned short* __restrict__ zcf_bf, float* __restrict__ hs,
    const float* __restrict__ att_w, const float* __restrict__ att_b,
    const float* __restrict__ att_vec, float* __restrict__ e_acc) {
    const int row = blockIdx.x, br = blockIdx.y, t = threadIdx.x;
    size_t base = ((size_t)br * 1024 + row) * 128;
    int n = cnts[br * 1024 + row];
    float acc = bias[t];
    const float* Xb = X + (size_t)br * 1024 * 64;
    for (int k = 0; k < n; ++k)
        acc += wts[base + k] * Xb[(size_t)idxs[base + k] * 64 + t];
    if (br == 0) {
        zcf_bf[(size_t)row * 64 + t] = f2bf(acc);
        return;
    }
    float s = acc * acc;
    #pragma unroll
    for (int o = 32; o; o >>= 1) s += __shfl_down(s, o);
    s = __shfl(s, 0);
    float v = acc * frcp(fmaxf(sqrtf(s), 1e-12f));
    hs[((size_t)(br - 1) * 1024 + row) * 64 + t] = v;
    // fused semantic-attention partial
    __shared__ float rs[64];
    rs[t] = v;
    __syncthreads();
    float sa = att_b[t];
    #pragma unroll
    for (int k = 0; k < 64; ++k) sa += rs[k] * att_w[k * 64 + t];
    float val = ftanh(sa) * att_vec[t];
    #pragma unroll
    for (int o = 32; o; o >>= 1) val += __shfl_down(val, o);
    if (t == 0) atomicAdd(&e_acc[br - 1], val);
}

// z_fine = sum_v beta_v hs[v]  (beta computed inline from e sums), bf16 out
__global__ void zfine_kernel(const float* __restrict__ hs, const float* __restrict__ small,
                             unsigned short* __restrict__ out) {
    int idx = blockIdx.x * 256 + threadIdx.x;
    if (idx < 65536) {
        float e0 = small[0] * (1.f / 1024.f), e1 = small[1] * (1.f / 1024.f);
        float e2 = small[2] * (1.f / 1024.f), e3 = small[3] * (1.f / 1024.f);
        float mx = fmaxf(fmaxf(e0, e1), fmaxf(e2, e3));
        float x0 = expf(e0 - mx), x1 = expf(e1 - mx), x2 = expf(e2 - mx), x3 = expf(e3 - mx);
        float inv = 1.f / (x0 + x1 + x2 + x3);
        float v = (x0 * hs[idx] + x1 * hs[idx + 65536] +
                   x2 * hs[idx + 131072] + x3 * hs[idx + 196608]) * inv;
        out[idx] = f2bf(v);
    }
}

// row l2norm in place + bf16 copy
__global__ __launch_bounds__(64) void l2normcast_kernel(float* __restrict__ X,
                                                        unsigned short* __restrict__ Xbf) {
    const int row = blockIdx.x, t = threadIdx.x;
    float v = X[(size_t)row * 64 + t];
    float s = v * v;
    #pragma unroll
    for (int o = 32; o; o >>= 1) s += __shfl_down(s, o);
    s = __shfl(s, 0);
    float r = v * frcp(fmaxf(sqrtf(s), 1e-12f));
    X[(size_t)row * 64 + t] = r;
    Xbf[(size_t)row * 64 + t] = f2bf(r);
}

// 4 anchors per block. denom_i = sum_j exp(2 zf_i.zc_j) * sigmoid(mlp(A1_i + C1_j))
__global__ __launch_bounds__(256) void infonce_kernel(
    const float* __restrict__ zf, const float* __restrict__ zc,
    const float* __restrict__ A1, const float* __restrict__ C1,
    const float* __restrict__ b1, const float* __restrict__ m2,
    const float* __restrict__ b2v, float* __restrict__ loss_acc) {
    const int i0 = blockIdx.x * 4, t = threadIdx.x;
    __shared__ __align__(16) float zfs[4][64];
    __shared__ float a1b[4][16], m2s[16];
    __shared__ float diag[4];
    __shared__ float wsum[4][4];
    if (t < 64) {
        #pragma unroll
        for (int ii = 0; ii < 4; ++ii) zfs[ii][t] = zf[(size_t)(i0 + ii) * 64 + t];
    }
    if (t < 16) {
        float bb = b1[t];
        #pragma unroll
        for (int ii = 0; ii < 4; ++ii) a1b[ii][t] = A1[(size_t)(i0 + ii) * 16 + t] + bb;
        m2s[t] = m2[t];
    }
    __syncthreads();
    const float b2 = b2v[0];
    float acc[4] = {};
    for (int j = t; j < 1024; j += 256) {
        const float4* zcj = reinterpret_cast<const float4*>(zc + (size_t)j * 64);
        float dot[4] = {};
        #pragma unroll
        for (int e = 0; e < 16; ++e) {
            float4 b = zcj[e];
            #pragma unroll
            for (int ii = 0; ii < 4; ++ii) {
                float4 a = reinterpret_cast<const float4*>(zfs[ii])[e];
                dot[ii] += a.x * b.x + a.y * b.y + a.z * b.z + a.w * b.w;
            }
        }
        float c1j[16];
        #pragma unroll
        for (int q = 0; q < 4; ++q) {
            float4 c4 = reinterpret_cast<const float4*>(C1 + (size_t)j * 16)[q];
            c1j[q * 4 + 0] = c4.x; c1j[q * 4 + 1] = c4.y;
            c1j[q * 4 + 2] = c4.z; c1j[q * 4 + 3] = c4.w;
        }
        #pragma unroll
        for (int ii = 0; ii < 4; ++ii) {
            float logit = dot[ii] * 2.0f; // 1/TAU
            float h = b2;
            #pragma unroll
            for (int k = 0; k < 16; ++k) h += ftanh(a1b[ii][k] + c1j[k]) * m2s[k];
            acc[ii] += fexp(logit) * fsigmoid(h);
            if (j == i0 + ii) diag[ii] = logit;
        }
    }
    #pragma unroll
    for (int ii = 0; ii < 4; ++ii) {
        float a = acc[ii];
        #pragma unroll
        for (int o = 32; o; o >>= 1) a += __shfl_down(a, o);
        if ((t & 63) == 0) wsum[t >> 6][ii] = a;
    }
    __syncthreads();
    if (t == 0) {
        float part = 0.f;
        #pragma unroll
        for (int ii = 0; ii < 4; ++ii) {
            float denom = wsum[0][ii] + wsum[1][ii] + wsum[2][ii] + wsum[3][ii];
            part += logf(denom) - diag[ii];
        }
        atomicAdd(loss_acc, part);
    }
}

__global__ void finalize_kernel(const float* __restrict__ small, float* __restrict__ out) {
    if (threadIdx.x == 0) out[0] = small[4] * (1.f / 1024.f);
}

extern "C" void kernel_launch(void* const* d_in, const int* in_sizes, int n_in,
                              void* d_out, int out_size, void* d_ws, size_t ws_size,
                              hipStream_t stream) {
    const float* feat0     = (const float*)d_in[0];
    const float* feat1     = (const float*)d_in[1];
    const float* feat2     = (const float*)d_in[2];
    const float* mask_feat = (const float*)d_in[3];
    const float* nei0      = (const float*)d_in[4];
    const float* nei1      = (const float*)d_in[5];
    const float* adj0      = (const float*)d_in[6];
    const float* adj1      = (const float*)d_in[7];
    const float* madj0     = (const float*)d_in[8];
    const float* madj1     = (const float*)d_in[9];
    const float* fc0_w = (const float*)d_in[10];
    const float* fc0_b = (const float*)d_in[11];
    const float* fc1_w = (const float*)d_in[12];
    const float* fc1_b = (const float*)d_in[13];
    const float* fc2_w = (const float*)d_in[14];
    const float* fc2_b = (const float*)d_in[15];
    const float* agg0_w = (const float*)d_in[16];
    const float* agg1_w = (const float*)d_in[17];
    const float* gcn_w1 = (const float*)d_in[18];
    const float* gcn_b1 = (const float*)d_in[19];
    const float* gcn_w2 = (const float*)d_in[20];
    const float* gcn_b2 = (const float*)d_in[21];
    const float* att_w  = (const float*)d_in[22];
    const float* att_b  = (const float*)d_in[23];
    const float* att_vec = (const float*)d_in[24];
    const float* proj_w = (const float*)d_in[25];
    const float* proj_b = (const float*)d_in[26];
    const float* mlp1_w = (const float*)d_in[27];
    const float* mlp1_b = (const float*)d_in[28];
    const float* mlp2_w = (const float*)d_in[29];
    const float* mlp2_b = (const float*)d_in[30];

    const int N = 1024, M = 4096, D0 = 1024, D1 = 512, H = 512, E = 64;
    typedef unsigned short bf;

    // ---- workspace ----
    float* W = (float*)d_ws;
    size_t off = 0;
    auto allocf = [&](size_t n) { float* p = W + off; off += n; return p; };
    float* h_tar   = allocf((size_t)N * H);
    float* h_mask  = allocf((size_t)N * H);
    float* tbuf    = allocf((size_t)2 * N * H);
    float* xw1cat  = allocf((size_t)5 * N * E);
    float* hw2cat  = allocf((size_t)5 * N * E);
    float* hs      = allocf((size_t)4 * N * E);
    float* zcat    = allocf((size_t)2 * N * E);
    float* AC1     = allocf((size_t)2 * N * 16);
    float* small   = allocf(16);
    float* adj_wts = allocf((size_t)5 * 1024 * 128);
    int*   adj_idx = (int*)allocf((size_t)5 * 1024 * 128);
    int*   adj_cnt = (int*)allocf((size_t)5 * 1024);
    bf* BP = (bf*)(W + off);
    size_t boff = 0;
    auto allocb = [&](size_t n) { bf* p = BP + boff; boff += n; return p; };
    bf* feat0_bf = allocb((size_t)N * D0);
    bf* mask_bf  = allocb((size_t)N * D0);
    bf* feat1_bf = allocb((size_t)M * D1);
    bf* feat2_bf = allocb((size_t)M * D1);
    bf* xcat_bf  = allocb((size_t)5 * N * H);
    bf* hnei0_bf = allocb((size_t)M * H);
    bf* hnei1_bf = allocb((size_t)M * H);
    bf* hagg_bf  = allocb((size_t)2 * N * H);
    bf* h1cat_bf = allocb((size_t)5 * N * E);
    bf* zcf_bf   = allocb((size_t)2 * N * E);
    bf* zcat_bf  = allocb((size_t)2 * N * E);
    bf* fc0_wT  = allocb((size_t)H * D0);
    bf* fc1_wT  = allocb((size_t)H * D1);
    bf* fc2_wT  = allocb((size_t)H * D1);
    bf* agg0_wT = allocb((size_t)H * H);
    bf* agg1_wT = allocb((size_t)H * H);
    bf* gw1_T   = allocb((size_t)E * H);
    bf* gw2_T   = allocb((size_t)E * E);
    bf* proj_wT = allocb((size_t)E * E);
    bf* mlp1_wT = allocb((size_t)16 * E);

    auto gemm = [&](const bf* A, const bf* Bt, const bf* Bt2, int msplit,
                    const float* bias, float* C, bf* Cbf, int Mm, int Kk, int Nn, int act) {
        dim3 g((Nn + 63) / 64, Mm / 64);
        gemm_bf16_kernel<<<g, 256, 0, stream>>>(A, Bt, Bt2, msplit, bias, C, Cbf, Mm, Kk, Nn, act);
    };

    hipMemsetAsync((void*)small, 0, 16 * sizeof(float), stream);

    // one batched transpose-cast for all 9 weights
    {
        CTArr a; int tile = 0, i = 0;
        auto add = [&](const float* in, bf* out, int R, int C) {
            int tc = (C + 31) / 32, trn = (R + 31) / 32;
            a.d[i++] = CTDesc{in, out, R, C, tc, tile};
            tile += tc * trn;
        };
        add(fc0_w, fc0_wT, D0, H);
        add(fc1_w, fc1_wT, D1, H);
        add(fc2_w, fc2_wT, D1, H);
        add(agg0_w, agg0_wT, H, H);
        add(agg1_w, agg1_wT, H, H);
        add(gcn_w1, gw1_T, H, E);
        add(gcn_w2, gw2_T, E, E);
        add(proj_w, proj_wT, E, E);
        add(mlp1_w, mlp1_wT, E, 16);
        a.n = i;
        castT_multi_kernel<<<tile, dim3(32, 8), 0, stream>>>(a);
    }
    // one batched flat cast for all 4 inputs
    {
        CMArr a; int s4 = 0, i = 0;
        auto add = [&](const float* in, bf* out, int n) {
            a.d[i++] = CMDesc{in, out, s4}; s4 += n / 4;
        };
        add(feat0, feat0_bf, N * D0);
        add(mask_feat, mask_bf, N * D0);
        add(feat1, feat1_bf, M * D1);
        add(feat2, feat2_bf, M * D1);
        a.n = i; a.total4 = s4;
        cast_multi_kernel<<<(s4 + 255) / 256, 256, 0, stream>>>(a);
    }
    // adjacency -> compact lists (shared by both spmm passes)
    adjprep_kernel<<<dim3(N, 5), 64, 0, stream>>>(adj0, adj1, madj0, madj1,
                                                  adj_cnt, adj_idx, adj_wts);

    // projections + ELU (h_tar also emits bf16 xcat branch 0; h_nei bf16-only)
    gemm(feat0_bf, fc0_wT, nullptr, 1 << 30, fc0_b, h_tar, xcat_bf, N, D0, H, ACT_ELU);
    gemm(mask_bf,  fc0_wT, nullptr, 1 << 30, fc0_b, h_mask, nullptr, N, D0, H, ACT_ELU);
    gemm(feat1_bf, fc1_wT, nullptr, 1 << 30, fc1_b, nullptr, hnei0_bf, M, D1, H, ACT_ELU);
    gemm(feat2_bf, fc2_wT, nullptr, 1 << 30, fc2_b, nullptr, hnei1_bf, M, D1, H, ACT_ELU);

    // meta-path aggregation (both paths in one dispatch each stage)
    neiagg_kernel<<<dim3(N, 2), 256, 0, stream>>>(nei0, nei1, hnei0_bf, hnei1_bf, hagg_bf);
    gemm(hagg_bf, agg0_wT, agg1_wT, N, nullptr, tbuf, nullptr, 2 * N, H, H, ACT_NONE);
    addelu_kernel<<<(N * H + 255) / 256, 256, 0, stream>>>(h_tar, h_mask, tbuf, xcat_bf, N * H);

    // batched GCN over 5 branches
    gemm(xcat_bf, gw1_T, nullptr, 1 << 30, nullptr, xw1cat, nullptr, 5 * N, H, E, ACT_NONE);
    spmm1_kernel<<<dim3(N, 5), 64, 0, stream>>>(adj_cnt, adj_idx, adj_wts, xw1cat, gcn_b1, h1cat_bf);
    gemm(h1cat_bf, gw2_T, nullptr, 1 << 30, nullptr, hw2cat, nullptr, 5 * N, E, E, ACT_NONE);
    spmm2_kernel<<<dim3(N, 5), 64, 0, stream>>>(adj_cnt, adj_idx, adj_wts, hw2cat, gcn_b2,
                                                zcf_bf, hs, att_w, att_b, att_vec, small);

    // z_fine with inline beta softmax
    zfine_kernel<<<(N * E + 255) / 256, 256, 0, stream>>>(hs, small, zcf_bf + (size_t)N * E);

    // projection head + fused l2norm/cast
    gemm(zcf_bf, proj_wT, nullptr, 1 << 30, proj_b, zcat, nullptr, 2 * N, E, E, ACT_TANH);
    l2normcast_kernel<<<2 * N, 64, 0, stream>>>(zcat, zcat_bf);

    // InfoNCE
    gemm(zcat_bf, mlp1_wT, nullptr, 1 << 30, nullptr, AC1, nullptr, 2 * N, E, 16, ACT_NONE);
    const float* zc = zcat;
    const float* zf = zcat + (size_t)N * E;
    const float* C1 = AC1;
    const float* A1 = AC1 + (size_t)N * 16;
    infonce_kernel<<<N / 4, 256, 0, stream>>>(zf, zc, A1, C1, mlp1_b, mlp2_w, mlp2_b, small + 4);

    finalize_kernel<<<1, 64, 0, stream>>>(small, (float*)d_out);
}

// Round 4
// 311.708 us; speedup vs baseline: 3.0700x; 1.2313x over previous
//
#include <hip/hip_runtime.h>

#define ACT_NONE 0
#define ACT_ELU  1
#define ACT_RELU 2
#define ACT_TANH 3

typedef __attribute__((ext_vector_type(8))) short short8;
typedef __attribute__((ext_vector_type(4))) float f32x4;

__device__ __forceinline__ float frcp(float x) { return __builtin_amdgcn_rcpf(x); }
__device__ __forceinline__ float fexp(float x) { return __expf(x); }
// safe fast tanh: 1 - 2/(e^2x + 1). x=+inf -> 1, x=-inf -> -1, no NaN.
__device__ __forceinline__ float ftanh(float x) {
    return 1.f - 2.f * frcp(fexp(2.f * x) + 1.f);
}
__device__ __forceinline__ float fsigmoid(float x) {
    return frcp(1.f + fexp(-x));
}

__device__ __forceinline__ float apply_act(float v, int act) {
    if (act == ACT_ELU)  return v > 0.f ? v : fexp(v) - 1.f;
    if (act == ACT_RELU) return fmaxf(v, 0.f);
    if (act == ACT_TANH) return ftanh(v);
    return v;
}

__device__ __forceinline__ unsigned short f2bf(float f) {
    unsigned int u = __float_as_uint(f);
    unsigned int r = (u + 0x7fffu + ((u >> 16) & 1u)) >> 16;
    return (unsigned short)r;
}
__device__ __forceinline__ float bf2f(unsigned short u) {
    return __uint_as_float(((unsigned int)u) << 16);
}

// ---------------- batched casts ----------------
struct CMDesc { const float* in; unsigned short* out; int start4; };
struct CMArr { CMDesc d[6]; int n; int total4; };

__global__ __launch_bounds__(256) void cast_multi_kernel(CMArr a) {
    int g4 = blockIdx.x * 256 + threadIdx.x;
    if (g4 >= a.total4) return;
    int s = 0;
    while (s + 1 < a.n && g4 >= a.d[s + 1].start4) ++s;
    int l4 = g4 - a.d[s].start4;
    float4 v = *reinterpret_cast<const float4*>(a.d[s].in + (size_t)l4 * 4);
    ushort4 o;
    o.x = f2bf(v.x); o.y = f2bf(v.y); o.z = f2bf(v.z); o.w = f2bf(v.w);
    *reinterpret_cast<ushort4*>(a.d[s].out + (size_t)l4 * 4) = o;
}

struct CTDesc { const float* in; unsigned short* out; int R, C, tcols, tile0; };
struct CTArr { CTDesc d[10]; int n; };

__global__ void castT_multi_kernel(CTArr a) {
    int b = blockIdx.x, s = 0;
    while (s + 1 < a.n && b >= a.d[s + 1].tile0) ++s;
    const CTDesc d = a.d[s];
    int lt = b - d.tile0;
    int tr = lt / d.tcols, tc = lt % d.tcols;
    int r0 = tr * 32, c0 = tc * 32;
    __shared__ float t[32][33];
    int tx = threadIdx.x, ty = threadIdx.y; // 32 x 8
    for (int i = ty; i < 32; i += 8) {
        int r = r0 + i, c = c0 + tx;
        t[i][tx] = (r < d.R && c < d.C) ? d.in[(size_t)r * d.C + c] : 0.f;
    }
    __syncthreads();
    for (int i = ty; i < 32; i += 8) {
        int c = c0 + i, r = r0 + tx;
        if (c < d.C && r < d.R) d.out[(size_t)c * d.R + r] = f2bf(t[tx][i]);
    }
}

// ---------------- MFMA GEMM ----------------
// C[M,N] = act(A@B + bias); A bf16 [M,K], Bt bf16 [N,K] pre-transposed.
// Rows >= m_split use Bt2/bias2. fp32 out C (optional) and/or bf16 out Cbf for
// rows < cbf_mlimit. M%64==0, K%32==0, N guarded.
__global__ __launch_bounds__(256) void gemm_bf16_kernel(
    const unsigned short* __restrict__ A, const unsigned short* __restrict__ Bt,
    const unsigned short* __restrict__ Bt2, int m_split,
    const float* __restrict__ bias, const float* __restrict__ bias2,
    float* __restrict__ C, unsigned short* __restrict__ Cbf, int cbf_mlimit,
    int M, int K, int N, int act) {
    const int tid = threadIdx.x;
    const int w = tid >> 6, lane = tid & 63;
    const int wr = w >> 1, wc = w & 1;
    const int lr = lane & 15, lk = lane >> 4;
    const int bm = blockIdx.y * 64, bn = blockIdx.x * 64;
    const unsigned short* Bu = Bt;
    const float* bu = bias;
    if (bm >= m_split) { Bu = Bt2; bu = bias2; }

    const int arow0 = bm + wr * 32 + lr;
    const int brow0 = bn + wc * 32 + lr;

    f32x4 acc[2][2] = {};
    const short8 zero8 = {};
    #pragma unroll 4
    for (int k0 = 0; k0 < K; k0 += 32) {
        short8 a[2], b[2];
        #pragma unroll
        for (int i = 0; i < 2; ++i)
            a[i] = *reinterpret_cast<const short8*>(&A[(size_t)(arow0 + i * 16) * K + k0 + lk * 8]);
        #pragma unroll
        for (int j = 0; j < 2; ++j) {
            int br = brow0 + j * 16;
            b[j] = (br < N) ? *reinterpret_cast<const short8*>(&Bu[(size_t)br * K + k0 + lk * 8])
                            : zero8;
        }
        #pragma unroll
        for (int i = 0; i < 2; ++i)
            #pragma unroll
            for (int j = 0; j < 2; ++j)
                acc[i][j] = __builtin_amdgcn_mfma_f32_16x16x32_bf16(a[i], b[j], acc[i][j], 0, 0, 0);
    }
    #pragma unroll
    for (int i = 0; i < 2; ++i) {
        #pragma unroll
        for (int j = 0; j < 2; ++j) {
            int gcol = bn + wc * 32 + j * 16 + lr;
            if (gcol >= N) continue;
            float bv = bu ? bu[gcol] : 0.f;
            #pragma unroll
            for (int r = 0; r < 4; ++r) {
                int grow = bm + wr * 32 + i * 16 + lk * 4 + r;
                float v = apply_act(acc[i][j][r] + bv, act);
                if (C)   C[(size_t)grow * N + gcol] = v;
                if (Cbf && grow < cbf_mlimit) Cbf[(size_t)grow * N + gcol] = f2bf(v);
            }
        }
    }
}

// ---------------- sparse ops ----------------
// both meta-paths: hagg[br] = mean of bf16 h_nei rows selected by nei row
__global__ __launch_bounds__(256) void neiagg_kernel(
    const float* __restrict__ nei0, const float* __restrict__ nei1,
    const unsigned short* __restrict__ hn0, const unsigned short* __restrict__ hn1,
    unsigned short* __restrict__ hagg) {
    const int row = blockIdx.x, br = blockIdx.y, t = threadIdx.x;
    const float* nei = br ? nei1 : nei0;
    const unsigned short* hn = br ? hn1 : hn0;
    __shared__ int idxs[256];
    __shared__ int cnt;
    if (t == 0) cnt = 0;
    __syncthreads();
    const float4* nr = reinterpret_cast<const float4*>(nei + (size_t)row * 4096);
    for (int j = t; j < 1024; j += 256) {
        float4 v = nr[j];
        if (v.x != 0.f) { int s = atomicAdd(&cnt, 1); if (s < 256) idxs[s] = j * 4 + 0; }
        if (v.y != 0.f) { int s = atomicAdd(&cnt, 1); if (s < 256) idxs[s] = j * 4 + 1; }
        if (v.z != 0.f) { int s = atomicAdd(&cnt, 1); if (s < 256) idxs[s] = j * 4 + 2; }
        if (v.w != 0.f) { int s = atomicAdd(&cnt, 1); if (s < 256) idxs[s] = j * 4 + 3; }
    }
    __syncthreads();
    int n = cnt < 256 ? cnt : 256;
    float inv = frcp(fmaxf((float)cnt, 1.f));
    // 2 cols per thread, 2 independent row-accumulators
    int c = t * 2;
    float a0 = 0.f, a1 = 0.f, b0 = 0.f, b1 = 0.f;
    int k = 0;
    for (; k + 2 <= n; k += 2) {
        ushort2 u = *reinterpret_cast<const ushort2*>(&hn[(size_t)idxs[k] * 512 + c]);
        ushort2 v = *reinterpret_cast<const ushort2*>(&hn[(size_t)idxs[k + 1] * 512 + c]);
        a0 += bf2f(u.x); a1 += bf2f(u.y);
        b0 += bf2f(v.x); b1 += bf2f(v.y);
    }
    if (k < n) {
        ushort2 u = *reinterpret_cast<const ushort2*>(&hn[(size_t)idxs[k] * 512 + c]);
        a0 += bf2f(u.x); a1 += bf2f(u.y);
    }
    ushort2 o; o.x = f2bf((a0 + b0) * inv); o.y = f2bf((a1 + b1) * inv);
    *reinterpret_cast<ushort2*>(&hagg[((size_t)br * 1024 + row) * 512 + c]) = o;
}

// views/masks for both meta-paths -> xcat branches 1..4 (bf16)
__global__ void addelu_kernel(const float* __restrict__ ht, const float* __restrict__ hm,
                              const float* __restrict__ tt, unsigned short* __restrict__ xcat,
                              int nh) {
    int idx = blockIdx.x * 256 + threadIdx.x;
    if (idx < nh) {
        float h1 = ht[idx], h2 = hm[idx];
        float t0 = tt[idx], t1 = tt[idx + nh];
        float a = h1 + t0, b = h2 + t0, c = h1 + t1, d = h2 + t1;
        xcat[(size_t)1 * nh + idx] = f2bf(a > 0.f ? a : fexp(a) - 1.f);
        xcat[(size_t)2 * nh + idx] = f2bf(b > 0.f ? b : fexp(b) - 1.f);
        xcat[(size_t)3 * nh + idx] = f2bf(c > 0.f ? c : fexp(c) - 1.f);
        xcat[(size_t)4 * nh + idx] = f2bf(d > 0.f ? d : fexp(d) - 1.f);
    }
}

// scan adjacency rows once into compact lists. br0 = 0.5*(adj0+adj1), 1=adj0, 2=madj0, 3=adj1, 4=madj1
__global__ __launch_bounds__(64) void adjprep_kernel(
    const float* __restrict__ adj0, const float* __restrict__ adj1,
    const float* __restrict__ madj0, const float* __restrict__ madj1,
    int* __restrict__ cnts, int* __restrict__ idxs, float* __restrict__ wts) {
    const int row = blockIdx.x, br = blockIdx.y, t = threadIdx.x;
    const float* Aa; const float* Ab = nullptr; float sc = 1.f;
    if (br == 0)      { Aa = adj0; Ab = adj1; sc = 0.5f; }
    else if (br == 1) { Aa = adj0; }
    else if (br == 2) { Aa = madj0; }
    else if (br == 3) { Aa = adj1; }
    else              { Aa = madj1; }
    __shared__ int li[128];
    __shared__ float lw[128];
    __shared__ int cnt;
    if (t == 0) cnt = 0;
    __syncthreads();
    const float4* ar = reinterpret_cast<const float4*>(Aa + (size_t)row * 1024);
    const float4* brp = Ab ? reinterpret_cast<const float4*>(Ab + (size_t)row * 1024) : nullptr;
    for (int j = t; j < 256; j += 64) {
        float4 v = ar[j];
        if (brp) { float4 u = brp[j]; v.x += u.x; v.y += u.y; v.z += u.z; v.w += u.w; }
        if (v.x != 0.f) { int s = atomicAdd(&cnt, 1); if (s < 128) { li[s] = j * 4 + 0; lw[s] = v.x * sc; } }
        if (v.y != 0.f) { int s = atomicAdd(&cnt, 1); if (s < 128) { li[s] = j * 4 + 1; lw[s] = v.y * sc; } }
        if (v.z != 0.f) { int s = atomicAdd(&cnt, 1); if (s < 128) { li[s] = j * 4 + 2; lw[s] = v.z * sc; } }
        if (v.w != 0.f) { int s = atomicAdd(&cnt, 1); if (s < 128) { li[s] = j * 4 + 3; lw[s] = v.w * sc; } }
    }
    __syncthreads();
    int n = cnt < 128 ? cnt : 128;
    size_t base = ((size_t)br * 1024 + row) * 128;
    for (int k = t; k < n; k += 64) { idxs[base + k] = li[k]; wts[base + k] = lw[k]; }
    if (t == 0) cnts[br * 1024 + row] = n;
}

__device__ __forceinline__ float sparse_gather(const int* __restrict__ idxs,
                                               const float* __restrict__ wts,
                                               size_t base, int n,
                                               const float* __restrict__ Xb, int t,
                                               float acc) {
    float a1 = 0.f, a2 = 0.f, a3 = 0.f;
    int k = 0;
    for (; k + 4 <= n; k += 4) {
        int   i0 = idxs[base + k],     i1 = idxs[base + k + 1];
        int   i2 = idxs[base + k + 2], i3 = idxs[base + k + 3];
        float w0 = wts[base + k],      w1 = wts[base + k + 1];
        float w2 = wts[base + k + 2],  w3 = wts[base + k + 3];
        acc += w0 * Xb[(size_t)i0 * 64 + t];
        a1  += w1 * Xb[(size_t)i1 * 64 + t];
        a2  += w2 * Xb[(size_t)i2 * 64 + t];
        a3  += w3 * Xb[(size_t)i3 * 64 + t];
    }
    for (; k < n; ++k) acc += wts[base + k] * Xb[(size_t)idxs[base + k] * 64 + t];
    return acc + a1 + a2 + a3;
}

// h1cat[br] = bf16(relu(adj_br @ X[br] + b1)), X [5][1024][64] fp32
__global__ __launch_bounds__(64) void spmm1_kernel(
    const int* __restrict__ cnts, const int* __restrict__ idxs, const float* __restrict__ wts,
    const float* __restrict__ X, const float* __restrict__ bias,
    unsigned short* __restrict__ out) {
    const int row = blockIdx.x, br = blockIdx.y, t = threadIdx.x;
    size_t base = ((size_t)br * 1024 + row) * 128;
    int n = cnts[br * 1024 + row];
    float acc = sparse_gather(idxs, wts, base, n, X + (size_t)br * 1024 * 64, t, bias[t]);
    out[((size_t)br * 1024 + row) * 64 + t] = f2bf(fmaxf(acc, 0.f));
}

// br0 -> zcf_bf (bf16, no norm); br1..4 -> hs[br-1] fp32 with fused l2norm + att row value
__global__ __launch_bounds__(64) void spmm2_kernel(
    const int* __restrict__ cnts, const int* __restrict__ idxs, const float* __restrict__ wts,
    const float* __restrict__ X, const float* __restrict__ bias,
    unsigned short* __restrict__ zcf_bf, float* __restrict__ hs,
    const float* __restrict__ att_w, const float* __restrict__ att_b,
    const float* __restrict__ att_vec, float* __restrict__ att_row) {
    const int row = blockIdx.x, br = blockIdx.y, t = threadIdx.x;
    size_t base = ((size_t)br * 1024 + row) * 128;
    int n = cnts[br * 1024 + row];
    float acc = sparse_gather(idxs, wts, base, n, X + (size_t)br * 1024 * 64, t, bias[t]);
    if (br == 0) {
        zcf_bf[(size_t)row * 64 + t] = f2bf(acc);
        return;
    }
    float s = acc * acc;
    #pragma unroll
    for (int o = 32; o; o >>= 1) s += __shfl_down(s, o);
    s = __shfl(s, 0);
    float v = acc * frcp(fmaxf(sqrtf(s), 1e-12f));
    hs[((size_t)(br - 1) * 1024 + row) * 64 + t] = v;
    // fused semantic-attention row value (no atomics: per-row store)
    __shared__ float rs[64];
    rs[t] = v;
    __syncthreads();
    float sa = att_b[t];
    #pragma unroll
    for (int k = 0; k < 64; ++k) sa += rs[k] * att_w[k * 64 + t];
    float val = ftanh(sa) * att_vec[t];
    #pragma unroll
    for (int o = 32; o; o >>= 1) val += __shfl_down(val, o);
    if (t == 0) att_row[(size_t)(br - 1) * 1024 + row] = val;
}

// small[v] = sum_row att_row[v][row], v in 0..3 (one block per v, no atomics)
__global__ __launch_bounds__(256) void attreduce_kernel(const float* __restrict__ att_row,
                                                        float* __restrict__ small) {
    const int v = blockIdx.x, t = threadIdx.x;
    const float* p = att_row + (size_t)v * 1024;
    float s = p[t] + p[t + 256] + p[t + 512] + p[t + 768];
    #pragma unroll
    for (int o = 32; o; o >>= 1) s += __shfl_down(s, o);
    __shared__ float ps[4];
    if ((t & 63) == 0) ps[t >> 6] = s;
    __syncthreads();
    if (t == 0) small[v] = ps[0] + ps[1] + ps[2] + ps[3];
}

// z_fine = sum_v beta_v hs[v]  (beta computed inline from e sums), bf16 out
__global__ void zfine_kernel(const float* __restrict__ hs, const float* __restrict__ small,
                             unsigned short* __restrict__ out) {
    int idx = blockIdx.x * 256 + threadIdx.x;
    if (idx < 65536) {
        float e0 = small[0] * (1.f / 1024.f), e1 = small[1] * (1.f / 1024.f);
        float e2 = small[2] * (1.f / 1024.f), e3 = small[3] * (1.f / 1024.f);
        float mx = fmaxf(fmaxf(e0, e1), fmaxf(e2, e3));
        float x0 = expf(e0 - mx), x1 = expf(e1 - mx), x2 = expf(e2 - mx), x3 = expf(e3 - mx);
        float inv = 1.f / (x0 + x1 + x2 + x3);
        float v = (x0 * hs[idx] + x1 * hs[idx + 65536] +
                   x2 * hs[idx + 131072] + x3 * hs[idx + 196608]) * inv;
        out[idx] = f2bf(v);
    }
}

// row l2norm in place + bf16 copy
__global__ __launch_bounds__(64) void l2normcast_kernel(float* __restrict__ X,
                                                        unsigned short* __restrict__ Xbf) {
    const int row = blockIdx.x, t = threadIdx.x;
    float v = X[(size_t)row * 64 + t];
    float s = v * v;
    #pragma unroll
    for (int o = 32; o; o >>= 1) s += __shfl_down(s, o);
    s = __shfl(s, 0);
    float r = v * frcp(fmaxf(sqrtf(s), 1e-12f));
    X[(size_t)row * 64 + t] = r;
    Xbf[(size_t)row * 64 + t] = f2bf(r);
}

// 4 anchors per block. denom_i = sum_j exp(2 zf_i.zc_j) * sigmoid(mlp(A1_i + C1_j))
__global__ __launch_bounds__(256) void infonce_kernel(
    const float* __restrict__ zf, const float* __restrict__ zc,
    const float* __restrict__ A1, const float* __restrict__ C1,
    const float* __restrict__ b1, const float* __restrict__ m2,
    const float* __restrict__ b2v, float* __restrict__ loss_acc) {
    const int i0 = blockIdx.x * 4, t = threadIdx.x;
    __shared__ __align__(16) float zfs[4][64];
    __shared__ float a1b[4][16], m2s[16];
    __shared__ float diag[4];
    __shared__ float wsum[4][4];
    if (t < 64) {
        #pragma unroll
        for (int ii = 0; ii < 4; ++ii) zfs[ii][t] = zf[(size_t)(i0 + ii) * 64 + t];
    }
    if (t < 16) {
        float bb = b1[t];
        #pragma unroll
        for (int ii = 0; ii < 4; ++ii) a1b[ii][t] = A1[(size_t)(i0 + ii) * 16 + t] + bb;
        m2s[t] = m2[t];
    }
    __syncthreads();
    const float b2 = b2v[0];
    float acc[4] = {};
    for (int j = t; j < 1024; j += 256) {
        const float4* zcj = reinterpret_cast<const float4*>(zc + (size_t)j * 64);
        float dot[4] = {};
        #pragma unroll
        for (int e = 0; e < 16; ++e) {
            float4 b = zcj[e];
            #pragma unroll
            for (int ii = 0; ii < 4; ++ii) {
                float4 a = reinterpret_cast<const float4*>(zfs[ii])[e];
                dot[ii] += a.x * b.x + a.y * b.y + a.z * b.z + a.w * b.w;
            }
        }
        float c1j[16];
        #pragma unroll
        for (int q = 0; q < 4; ++q) {
            float4 c4 = reinterpret_cast<const float4*>(C1 + (size_t)j * 16)[q];
            c1j[q * 4 + 0] = c4.x; c1j[q * 4 + 1] = c4.y;
            c1j[q * 4 + 2] = c4.z; c1j[q * 4 + 3] = c4.w;
        }
        #pragma unroll
        for (int ii = 0; ii < 4; ++ii) {
            float logit = dot[ii] * 2.0f; // 1/TAU
            float h = b2;
            #pragma unroll
            for (int k = 0; k < 16; ++k) h += ftanh(a1b[ii][k] + c1j[k]) * m2s[k];
            acc[ii] += fexp(logit) * fsigmoid(h);
            if (j == i0 + ii) diag[ii] = logit;
        }
    }
    #pragma unroll
    for (int ii = 0; ii < 4; ++ii) {
        float a = acc[ii];
        #pragma unroll
        for (int o = 32; o; o >>= 1) a += __shfl_down(a, o);
        if ((t & 63) == 0) wsum[t >> 6][ii] = a;
    }
    __syncthreads();
    if (t == 0) {
        float part = 0.f;
        #pragma unroll
        for (int ii = 0; ii < 4; ++ii) {
            float denom = wsum[0][ii] + wsum[1][ii] + wsum[2][ii] + wsum[3][ii];
            part += logf(denom) - diag[ii];
        }
        atomicAdd(loss_acc, part);
    }
}

__global__ void finalize_kernel(const float* __restrict__ small, float* __restrict__ out) {
    if (threadIdx.x == 0) out[0] = small[4] * (1.f / 1024.f);
}

extern "C" void kernel_launch(void* const* d_in, const int* in_sizes, int n_in,
                              void* d_out, int out_size, void* d_ws, size_t ws_size,
                              hipStream_t stream) {
    const float* feat0     = (const float*)d_in[0];
    const float* feat1     = (const float*)d_in[1];
    const float* feat2     = (const float*)d_in[2];
    const float* mask_feat = (const float*)d_in[3];
    const float* nei0      = (const float*)d_in[4];
    const float* nei1      = (const float*)d_in[5];
    const float* adj0      = (const float*)d_in[6];
    const float* adj1      = (const float*)d_in[7];
    const float* madj0     = (const float*)d_in[8];
    const float* madj1     = (const float*)d_in[9];
    const float* fc0_w = (const float*)d_in[10];
    const float* fc0_b = (const float*)d_in[11];
    const float* fc1_w = (const float*)d_in[12];
    const float* fc1_b = (const float*)d_in[13];
    const float* fc2_w = (const float*)d_in[14];
    const float* fc2_b = (const float*)d_in[15];
    const float* agg0_w = (const float*)d_in[16];
    const float* agg1_w = (const float*)d_in[17];
    const float* gcn_w1 = (const float*)d_in[18];
    const float* gcn_b1 = (const float*)d_in[19];
    const float* gcn_w2 = (const float*)d_in[20];
    const float* gcn_b2 = (const float*)d_in[21];
    const float* att_w  = (const float*)d_in[22];
    const float* att_b  = (const float*)d_in[23];
    const float* att_vec = (const float*)d_in[24];
    const float* proj_w = (const float*)d_in[25];
    const float* proj_b = (const float*)d_in[26];
    const float* mlp1_w = (const float*)d_in[27];
    const float* mlp1_b = (const float*)d_in[28];
    const float* mlp2_w = (const float*)d_in[29];
    const float* mlp2_b = (const float*)d_in[30];

    const int N = 1024, M = 4096, D0 = 1024, D1 = 512, H = 512, E = 64;
    typedef unsigned short bf;

    // ---- workspace ----
    float* W = (float*)d_ws;
    size_t off = 0;
    auto allocf = [&](size_t n) { float* p = W + off; off += n; return p; };
    float* h_tar   = allocf((size_t)N * H);  // h_tar | h_mask contiguous
    float* h_mask  = allocf((size_t)N * H);
    float* tbuf    = allocf((size_t)2 * N * H);
    float* xw1cat  = allocf((size_t)5 * N * E);
    float* hw2cat  = allocf((size_t)5 * N * E);
    float* hs      = allocf((size_t)4 * N * E);
    float* zcat    = allocf((size_t)2 * N * E);
    float* AC1     = allocf((size_t)2 * N * 16);
    float* att_row = allocf((size_t)4 * N);
    float* small   = allocf(16);
    float* adj_wts = allocf((size_t)5 * 1024 * 128);
    int*   adj_idx = (int*)allocf((size_t)5 * 1024 * 128);
    int*   adj_cnt = (int*)allocf((size_t)5 * 1024);
    bf* BP = (bf*)(W + off);
    size_t boff = 0;
    auto allocb = [&](size_t n) { bf* p = BP + boff; boff += n; return p; };
    bf* feat0_bf = allocb((size_t)N * D0);   // feat0 | mask contiguous
    bf* mask_bf  = allocb((size_t)N * D0);
    bf* feat1_bf = allocb((size_t)M * D1);   // feat1 | feat2 contiguous
    bf* feat2_bf = allocb((size_t)M * D1);
    bf* xcat_bf  = allocb((size_t)5 * N * H);
    bf* hnei0_bf = allocb((size_t)M * H);    // hnei0 | hnei1 contiguous
    bf* hnei1_bf = allocb((size_t)M * H);
    bf* hagg_bf  = allocb((size_t)2 * N * H);
    bf* h1cat_bf = allocb((size_t)5 * N * E);
    bf* zcf_bf   = allocb((size_t)2 * N * E);
    bf* zcat_bf  = allocb((size_t)2 * N * E);
    bf* fc0_wT  = allocb((size_t)H * D0);
    bf* fc1_wT  = allocb((size_t)H * D1);
    bf* fc2_wT  = allocb((size_t)H * D1);
    bf* agg0_wT = allocb((size_t)H * H);
    bf* agg1_wT = allocb((size_t)H * H);
    bf* gw1_T   = allocb((size_t)E * H);
    bf* gw2_T   = allocb((size_t)E * E);
    bf* proj_wT = allocb((size_t)E * E);
    bf* mlp1_wT = allocb((size_t)16 * E);

    auto gemm = [&](const bf* A, const bf* Bt, const bf* Bt2, int msplit,
                    const float* bias, const float* bias2, float* C, bf* Cbf, int cbf_lim,
                    int Mm, int Kk, int Nn, int act) {
        dim3 g((Nn + 63) / 64, Mm / 64);
        gemm_bf16_kernel<<<g, 256, 0, stream>>>(A, Bt, Bt2, msplit, bias, bias2,
                                                C, Cbf, cbf_lim, Mm, Kk, Nn, act);
    };

    hipMemsetAsync((void*)small, 0, 16 * sizeof(float), stream);

    // one batched transpose-cast for all 9 weights
    {
        CTArr a; int tile = 0, i = 0;
        auto add = [&](const float* in, bf* out, int R, int C) {
            int tc = (C + 31) / 32, trn = (R + 31) / 32;
            a.d[i++] = CTDesc{in, out, R, C, tc, tile};
            tile += tc * trn;
        };
        add(fc0_w, fc0_wT, D0, H);
        add(fc1_w, fc1_wT, D1, H);
        add(fc2_w, fc2_wT, D1, H);
        add(agg0_w, agg0_wT, H, H);
        add(agg1_w, agg1_wT, H, H);
        add(gcn_w1, gw1_T, H, E);
        add(gcn_w2, gw2_T, E, E);
        add(proj_w, proj_wT, E, E);
        add(mlp1_w, mlp1_wT, E, 16);
        a.n = i;
        castT_multi_kernel<<<tile, dim3(32, 8), 0, stream>>>(a);
    }
    // one batched flat cast for all 4 inputs
    {
        CMArr a; int s4 = 0, i = 0;
        auto add = [&](const float* in, bf* out, int n) {
            a.d[i++] = CMDesc{in, out, s4}; s4 += n / 4;
        };
        add(feat0, feat0_bf, N * D0);
        add(mask_feat, mask_bf, N * D0);
        add(feat1, feat1_bf, M * D1);
        add(feat2, feat2_bf, M * D1);
        a.n = i; a.total4 = s4;
        cast_multi_kernel<<<(s4 + 255) / 256, 256, 0, stream>>>(a);
    }
    // adjacency -> compact lists (shared by both spmm passes)
    adjprep_kernel<<<dim3(N, 5), 64, 0, stream>>>(adj0, adj1, madj0, madj1,
                                                  adj_cnt, adj_idx, adj_wts);

    // projections + ELU (merged dispatches; h_tar rows also emit bf16 xcat branch 0)
    gemm(feat0_bf, fc0_wT, nullptr, 1 << 30, fc0_b, nullptr,
         h_tar, xcat_bf, N, 2 * N, D0, H, ACT_ELU);                 // [feat0;mask] -> [h_tar;h_mask]
    gemm(feat1_bf, fc1_wT, fc2_wT, M, fc1_b, fc2_b,
         nullptr, hnei0_bf, 2 * M, 2 * M, D1, H, ACT_ELU);          // [feat1;feat2] -> [hnei0;hnei1]

    // meta-path aggregation (both paths per dispatch)
    neiagg_kernel<<<dim3(N, 2), 256, 0, stream>>>(nei0, nei1, hnei0_bf, hnei1_bf, hagg_bf);
    gemm(hagg_bf, agg0_wT, agg1_wT, N, nullptr, nullptr,
         tbuf, nullptr, 0, 2 * N, H, H, ACT_NONE);
    addelu_kernel<<<(N * H + 255) / 256, 256, 0, stream>>>(h_tar, h_mask, tbuf, xcat_bf, N * H);

    // batched GCN over 5 branches
    gemm(xcat_bf, gw1_T, nullptr, 1 << 30, nullptr, nullptr,
         xw1cat, nullptr, 0, 5 * N, H, E, ACT_NONE);
    spmm1_kernel<<<dim3(N, 5), 64, 0, stream>>>(adj_cnt, adj_idx, adj_wts, xw1cat, gcn_b1, h1cat_bf);
    gemm(h1cat_bf, gw2_T, nullptr, 1 << 30, nullptr, nullptr,
         hw2cat, nullptr, 0, 5 * N, E, E, ACT_NONE);
    spmm2_kernel<<<dim3(N, 5), 64, 0, stream>>>(adj_cnt, adj_idx, adj_wts, hw2cat, gcn_b2,
                                                zcf_bf, hs, att_w, att_b, att_vec, att_row);
    attreduce_kernel<<<4, 256, 0, stream>>>(att_row, small);

    // z_fine with inline beta softmax
    zfine_kernel<<<(N * E + 255) / 256, 256, 0, stream>>>(hs, small, zcf_bf + (size_t)N * E);

    // projection head + fused l2norm/cast
    gemm(zcf_bf, proj_wT, nullptr, 1 << 30, proj_b, nullptr,
         zcat, nullptr, 0, 2 * N, E, E, ACT_TANH);
    l2normcast_kernel<<<2 * N, 64, 0, stream>>>(zcat, zcat_bf);

    // InfoNCE
    gemm(zcat_bf, mlp1_wT, nullptr, 1 << 30, nullptr, nullptr,
         AC1, nullptr, 0, 2 * N, E, 16, ACT_NONE);
    const float* zc = zcat;
    const float* zf = zcat + (size_t)N * E;
    const float* C1 = AC1;
    const float* A1 = AC1 + (size_t)N * 16;
    infonce_kernel<<<N / 4, 256, 0, stream>>>(zf, zc, A1, C1, mlp1_b, mlp2_w, mlp2_b, small + 4);

    finalize_kernel<<<1, 64, 0, stream>>>(small, (float*)d_out);
}